// Round 11
// baseline (1134.113 us; speedup 1.0000x reference)
//
#include <hip/hip_runtime.h>

#define LTOT 2048
#define BATCH 2
#define NTOK 4096
#define DMODEL 2048
#define DSTATE 128
#define NH 64
#define HD 64
#define DINNER 4096
#define CONVD 4352
#define XDTC 4416
#define INP 8512
#define INTER_ 5632
#define CHUNK_ 128
#define NCH 16
#define EPSF 1e-6f

typedef __bf16 bf16x8 __attribute__((ext_vector_type(8)));
typedef float f32x4 __attribute__((ext_vector_type(4)));
typedef unsigned short u16x4 __attribute__((ext_vector_type(4)));
typedef unsigned short u16x8 __attribute__((ext_vector_type(8)));

__device__ __forceinline__ unsigned short f2b(float f){
  unsigned int u = __builtin_bit_cast(unsigned int, f);
  u += 0x7fffu + ((u >> 16) & 1u);
  return (unsigned short)(u >> 16);
}
__device__ __forceinline__ float b2f(unsigned short h){
  return __builtin_bit_cast(float, ((unsigned int)h) << 16);
}
__device__ __forceinline__ f32x4 mfma16(bf16x8 a, bf16x8 b, f32x4 c){
  return __builtin_amdgcn_mfma_f32_16x16x32_bf16(a, b, c, 0, 0, 0);
}
// async global->LDS, 16B per lane, wave-uniform LDS base + lane*16
typedef const __attribute__((address_space(1))) void* gas_t;
typedef __attribute__((address_space(3))) void* las_t;
__device__ __forceinline__ void gload16(const void* g, void* l){
  __builtin_amdgcn_global_load_lds((gas_t)g, (las_t)l, 16, 0, 0);
}

// Swizzle (refcheck-verified R10): LDS(row,g) = global(row, g ^ (row&3) ^ ((row>>2)&3)).
// Staging pre-permutes the per-lane global source group; reads XOR the same terms.

// ---------------- weight convert: fp32 W[K][N] -> bf16 WT[Npad][K], zero rows n>=N ----------------
__global__ __launch_bounds__(256) void wconv_kernel(const float* __restrict__ W,
                                                    unsigned short* __restrict__ WT,
                                                    int K, int N)
{
  __shared__ unsigned short t[64][72];
  int n0 = blockIdx.x * 64, k0 = blockIdx.y * 64;
  int tid = threadIdx.x;
  int kl = tid >> 4, nl4 = (tid & 15) * 4;
  #pragma unroll
  for (int it = 0; it < 4; it++){
    int kk = kl + it * 16;
    float4 v = make_float4(0.f, 0.f, 0.f, 0.f);
    if (n0 < N) v = *(const float4*)&W[(size_t)(k0 + kk) * N + n0 + nl4];
    t[nl4 + 0][kk] = f2b(v.x);
    t[nl4 + 1][kk] = f2b(v.y);
    t[nl4 + 2][kk] = f2b(v.z);
    t[nl4 + 3][kk] = f2b(v.w);
  }
  __syncthreads();
  int nr = tid >> 3, k8 = (tid & 7) * 8;
  #pragma unroll
  for (int it = 0; it < 2; it++){
    int nn = nr + it * 32;
    *(u16x8*)&WT[(size_t)(n0 + nn) * K + k0 + k8] = *(const u16x8*)&t[nn][k8];
  }
}

// ---------------- RMSNorm: fp32 in -> bf16 out ----------------
__global__ __launch_bounds__(256) void rms_kernel(const float* __restrict__ x,
                                                  const float* __restrict__ w,
                                                  unsigned short* __restrict__ out, int width)
{
  int row = blockIdx.x, tid = threadIdx.x;
  const float* xr = x + (size_t)row * width;
  unsigned short* orow = out + (size_t)row * width;
  int nv = width >> 2;
  float ss = 0.f;
  for (int i = tid; i < nv; i += 256){
    float4 v = ((const float4*)xr)[i];
    ss += v.x*v.x + v.y*v.y + v.z*v.z + v.w*v.w;
  }
  #pragma unroll
  for (int off = 32; off > 0; off >>= 1) ss += __shfl_down(ss, off, 64);
  __shared__ float red[4];
  if ((tid & 63) == 0) red[tid >> 6] = ss;
  __syncthreads();
  float tot = red[0] + red[1] + red[2] + red[3];
  float scale = rsqrtf(tot / (float)width + EPSF);
  for (int i = tid; i < nv; i += 256){
    float4 v = ((const float4*)xr)[i];
    float4 wv = ((const float4*)w)[i];
    u16x4 o = { f2b(v.x * scale * wv.x), f2b(v.y * scale * wv.y),
                f2b(v.z * scale * wv.z), f2b(v.w * scale * wv.w) };
    ((u16x4*)orow)[i] = o;
  }
}

// ---------------- Gated RMSNorm: y fp32, z bf16 -> out bf16 ----------------
__global__ __launch_bounds__(256) void rms_gated_kernel(const float* __restrict__ y,
                                                        const unsigned short* __restrict__ z,
                                                        const float* __restrict__ w,
                                                        unsigned short* __restrict__ out)
{
  int row = blockIdx.x, tid = threadIdx.x;
  const float* yr = y + (size_t)row * DINNER;
  const unsigned short* zr = z + (size_t)row * DINNER;
  unsigned short* orow = out + (size_t)row * DINNER;
  float g[16];
  float ss = 0.f;
  #pragma unroll
  for (int ii = 0; ii < 4; ii++){
    int i = tid + ii * 256;
    float4 yv = ((const float4*)yr)[i];
    u16x4 zv = ((const u16x4*)zr)[i];
    #pragma unroll
    for (int e = 0; e < 4; e++){
      float zf = b2f(zv[e]);
      float yf = (&yv.x)[e];
      float gg = yf * (zf / (1.f + expf(-zf)));
      g[ii * 4 + e] = gg;
      ss += gg * gg;
    }
  }
  #pragma unroll
  for (int off = 32; off > 0; off >>= 1) ss += __shfl_down(ss, off, 64);
  __shared__ float red[4];
  if ((tid & 63) == 0) red[tid >> 6] = ss;
  __syncthreads();
  float tot = red[0] + red[1] + red[2] + red[3];
  float scale = rsqrtf(tot / (float)DINNER + EPSF);
  #pragma unroll
  for (int ii = 0; ii < 4; ii++){
    int i = tid + ii * 256;
    float4 wv = ((const float4*)w)[i];
    u16x4 o;
    #pragma unroll
    for (int e = 0; e < 4; e++) o[e] = f2b(g[ii * 4 + e] * scale * (&wv.x)[e]);
    ((u16x4*)orow)[i] = o;
  }
}

// ---------------- SwiGLU combine: g = silu(g) * u, bf16 ----------------
__global__ __launch_bounds__(256) void act_kernel(unsigned short* __restrict__ g,
                                                  const unsigned short* __restrict__ u, int n8)
{
  int stride = gridDim.x * 256;
  for (int i = blockIdx.x * 256 + threadIdx.x; i < n8; i += stride){
    u16x8 gv = ((const u16x8*)g)[i];
    u16x8 uv = ((const u16x8*)u)[i];
    u16x8 o;
    #pragma unroll
    for (int e = 0; e < 8; e++){
      float gf = b2f(gv[e]);
      o[e] = f2b(gf / (1.f + expf(-gf)) * b2f(uv[e]));
    }
    ((u16x8*)g)[i] = o;
  }
}

// ---------------- GEMM9: 256x256, BK=32, 8 waves, 3x32KB bufs, TWO phases per K-tile -----------
// m201-style phase schedule: per phase {ds-reads (4-8 b128) || 2 gloads of tile t+2 -> barrier ->
// setprio(1) 16-MFMA cluster setprio(0) -> [vmcnt(4) counted at tile end] -> barrier}.
// Phase rendezvous creates wave role-split so reads of one wave overlap MFMA of another (T3+T5);
// counted vmcnt keeps 4 loads in flight across barriers (T4). Hazards as gemm3 (proven R8-R9).
__global__ __launch_bounds__(512, 1) void gemm9_kernel(const unsigned short* __restrict__ A,
                                                       const unsigned short* __restrict__ BT,
                                                       const float* __restrict__ addsrc,
                                                       float* __restrict__ Cf,
                                                       unsigned short* __restrict__ Cb,
                                                       unsigned short* __restrict__ Cb2, int splitN,
                                                       const unsigned short* __restrict__ gate,
                                                       float* __restrict__ dtraw,
                                                       int M, int N, int K)
{
  extern __shared__ unsigned short lds[];    // 49152 u16 = 96KB; buf i at i*16384 (A 8192, B 8192)
  int tid = threadIdx.x, lane = tid & 63, w = tid >> 6;
  int wm = w >> 2, wn = w & 3;               // wave grid 2(M) x 4(N); wave block 128x64
  int bid = blockIdx.x + blockIdx.y * gridDim.x;
  int nwg = gridDim.x * gridDim.y;
  int q8 = nwg >> 3, r8 = nwg & 7;
  int xcd = bid & 7, boff = bid >> 3;
  int wgid = (xcd < r8 ? xcd * (q8 + 1) : r8 * (q8 + 1) + (xcd - r8) * q8) + boff;
  int bn = (wgid % gridDim.x) * 256;
  int bm = (wgid / gridDim.x) * 256;

  int gsrc = (((lane & 3) ^ ((lane >> 2) & 3) ^ ((4 * w + (lane >> 4)) & 3)) << 3);
  int prow_l = lane >> 2;
  int ko = (((lane >> 4) ^ (lane & 3) ^ ((lane >> 2) & 3)) << 3);
  int rsel = (lane & 15) * 32 + ko;

  f32x4 acc[8][4] = {};
  int NT = K >> 5;

  // A-lines (rows 0-127, 128-255) and B-lines of K-tile kt into buffer bsel
  #define STAGE_A(kt, bsel)                                                                  \
    {                                                                                        \
      unsigned short* bA_ = &lds[(bsel) * 16384];                                            \
      size_t k0_ = (size_t)(kt) << 5;                                                        \
      gload16(&A [(size_t)(bm +       w * 16 + prow_l) * K + k0_ + gsrc], &bA_[w * 512]);    \
      gload16(&A [(size_t)(bm + 128 + w * 16 + prow_l) * K + k0_ + gsrc], &bA_[4096 + w * 512]); \
    }
  #define STAGE_B(kt, bsel)                                                                  \
    {                                                                                        \
      unsigned short* bB_ = &lds[(bsel) * 16384 + 8192];                                     \
      size_t k0_ = (size_t)(kt) << 5;                                                        \
      gload16(&BT[(size_t)(bn +       w * 16 + prow_l) * K + k0_ + gsrc], &bB_[w * 512]);    \
      gload16(&BT[(size_t)(bn + 128 + w * 16 + prow_l) * K + k0_ + gsrc], &bB_[4096 + w * 512]); \
    }

  STAGE_A(0, 0) STAGE_B(0, 0)
  STAGE_A(1, 1) STAGE_B(1, 1)
  asm volatile("s_waitcnt vmcnt(4)" ::: "memory");   // tile 0's 4 landed; tile 1 in flight
  __builtin_amdgcn_s_barrier();
  asm volatile("" ::: "memory");

  for (int t = 0; t < NT; ++t){
    const unsigned short* bA = &lds[(t % 3) * 16384];
    const unsigned short* bB = bA + 8192;
    bool pf = (t + 2 < NT);
    int bs2 = (t + 2) % 3;
    // ---- phase 0: A rows 0-63 of wave block + all B frags; stage t+2 A-lines ----
    bf16x8 afr[4], bfr[4];
    #pragma unroll
    for (int i = 0; i < 4; ++i)
      afr[i] = *(const bf16x8*)&bA[(wm * 128 + i * 16) * 32 + rsel];
    #pragma unroll
    for (int c = 0; c < 4; ++c)
      bfr[c] = *(const bf16x8*)&bB[(wn * 64 + c * 16) * 32 + rsel];
    if (pf) STAGE_A(t + 2, bs2)
    asm volatile("" ::: "memory");
    __builtin_amdgcn_s_barrier();
    asm volatile("" ::: "memory");
    __builtin_amdgcn_s_setprio(1);
    #pragma unroll
    for (int i = 0; i < 4; ++i)
      #pragma unroll
      for (int c = 0; c < 4; ++c)
        acc[i][c] = mfma16(afr[i], bfr[c], acc[i][c]);
    __builtin_amdgcn_s_setprio(0);
    asm volatile("" ::: "memory");
    __builtin_amdgcn_s_barrier();
    asm volatile("" ::: "memory");
    // ---- phase 1: A rows 64-127; stage t+2 B-lines; counted vmcnt at tile end ----
    bf16x8 afr2[4];
    #pragma unroll
    for (int i = 0; i < 4; ++i)
      afr2[i] = *(const bf16x8*)&bA[(wm * 128 + (i + 4) * 16) * 32 + rsel];
    if (pf) STAGE_B(t + 2, bs2)
    asm volatile("" ::: "memory");
    __builtin_amdgcn_s_barrier();
    asm volatile("" ::: "memory");
    __builtin_amdgcn_s_setprio(1);
    #pragma unroll
    for (int i = 0; i < 4; ++i)
      #pragma unroll
      for (int c = 0; c < 4; ++c)
        acc[i + 4][c] = mfma16(afr2[i], bfr[c], acc[i + 4][c]);
    __builtin_amdgcn_s_setprio(0);
    if (pf)              asm volatile("s_waitcnt vmcnt(4)" ::: "memory");  // t+1 landed
    else if (t + 1 < NT) asm volatile("s_waitcnt vmcnt(0)" ::: "memory");  // final drain
    asm volatile("" ::: "memory");
    __builtin_amdgcn_s_barrier();
    asm volatile("" ::: "memory");
  }
  #undef STAGE_A
  #undef STAGE_B

  int r0 = bm + wm * 128 + ((lane >> 4) << 2);
  int c0 = bn + wn * 64 + (lane & 15);
  #pragma unroll
  for (int i = 0; i < 8; ++i){
    #pragma unroll
    for (int j = 0; j < 4; ++j){
      int cc = c0 + j * 16;
      if (cc < N){
        #pragma unroll
        for (int e = 0; e < 4; ++e){
          int rr = r0 + i * 16 + e;
          float v = acc[i][j][e];
          if (Cf){
            size_t idx = (size_t)rr * N + cc;
            if (addsrc) v += addsrc[idx];
            Cf[idx] = v;
          } else if (cc < splitN){
            size_t idx = (size_t)rr * splitN + cc;
            float vv = v;
            if (gate){ float gg = b2f(gate[idx]); vv = gg / (1.f + expf(-gg)) * v; }
            Cb[idx] = f2b(vv);
          } else {
            Cb2[(size_t)rr * (N - splitN) + (cc - splitN)] = f2b(v);
            if (dtraw && cc >= N - NH) dtraw[(size_t)rr * NH + (cc - (N - NH))] = v;
          }
        }
      }
    }
  }
}

// ---------------- GEMM4: 128(M)x128(N), BK=32, 4 waves (2x2), 3x16KB bufs -> 3 blocks/CU -------
__global__ __launch_bounds__(256, 3) void gemm4_kernel(const unsigned short* __restrict__ A,
                                                       const unsigned short* __restrict__ BT,
                                                       const float* __restrict__ addsrc,
                                                       float* __restrict__ Cf,
                                                       int M, int N, int K)
{
  extern __shared__ unsigned short lds[];    // 24576 u16 = 48KB; buf i at i*8192 (A 4096, B 4096)
  int tid = threadIdx.x, lane = tid & 63, w = tid >> 6;
  int wm = w >> 1, wn = w & 1;               // wave grid 2(M) x 2(N); wave block 64x64
  int bid = blockIdx.x + blockIdx.y * gridDim.x;
  int nwg = gridDim.x * gridDim.y;
  int q8 = nwg >> 3, r8 = nwg & 7;
  int xcd = bid & 7, boff = bid >> 3;
  int wgid = (xcd < r8 ? xcd * (q8 + 1) : r8 * (q8 + 1) + (xcd - r8) * q8) + boff;
  int bn = (wgid % gridDim.x) * 128;
  int bm = (wgid / gridDim.x) * 128;

  int gsrc = (((lane & 3) ^ ((lane >> 2) & 3) ^ ((4 * w + (lane >> 4)) & 3)) << 3);
  int prow_l = lane >> 2;
  int ko = (((lane >> 4) ^ (lane & 3) ^ ((lane >> 2) & 3)) << 3);
  int rsel = (lane & 15) * 32 + ko;

  f32x4 acc[4][4] = {};
  int NT = K >> 5;

  #define STAGE4(kt, bsel)                                                             \
    {                                                                                  \
      unsigned short* bb_ = &lds[(bsel) * 8192];                                       \
      size_t k0_ = (size_t)(kt) << 5;                                                  \
      gload16(&A [(size_t)(bm +      w * 16 + prow_l) * K + k0_ + gsrc], &bb_[w * 512]);          \
      gload16(&A [(size_t)(bm + 64 + w * 16 + prow_l) * K + k0_ + gsrc], &bb_[2048 + w * 512]);   \
      gload16(&BT[(size_t)(bn +      w * 16 + prow_l) * K + k0_ + gsrc], &bb_[4096 + w * 512]);   \
      gload16(&BT[(size_t)(bn + 64 + w * 16 + prow_l) * K + k0_ + gsrc], &bb_[6144 + w * 512]);   \
    }

  STAGE4(0, 0)
  STAGE4(1, 1)
  asm volatile("s_waitcnt vmcnt(4)" ::: "memory");
  __builtin_amdgcn_s_barrier();
  asm volatile("" ::: "memory");

  for (int t = 0; t < NT; ++t){
    const unsigned short* bufc = &lds[(t % 3) * 8192];
    bf16x8 afr[4], bfr[4];
    #pragma unroll
    for (int i = 0; i < 4; ++i)
      afr[i] = *(const bf16x8*)&bufc[(wm * 64 + i * 16) * 32 + rsel];
    #pragma unroll
    for (int c = 0; c < 4; ++c)
      bfr[c] = *(const bf16x8*)&bufc[4096 + (wn * 64 + c * 16) * 32 + rsel];
    if (t + 2 < NT) STAGE4(t + 2, (t + 2) % 3)
    __builtin_amdgcn_s_setprio(1);
    #pragma unroll
    for (int i = 0; i < 4; ++i)
      #pragma unroll
      for (int c = 0; c < 4; ++c)
        acc[i][c] = mfma16(afr[i], bfr[c], acc[i][c]);
    __builtin_amdgcn_s_setprio(0);
    if (t + 2 < NT)      asm volatile("s_waitcnt vmcnt(4)" ::: "memory");
    else if (t + 1 < NT) asm volatile("s_waitcnt vmcnt(0)" ::: "memory");
    asm volatile("" ::: "memory");
    __builtin_amdgcn_s_barrier();
    asm volatile("" ::: "memory");
  }
  #undef STAGE4

  int r0 = bm + wm * 64 + ((lane >> 4) << 2);
  int c0 = bn + wn * 64 + (lane & 15);
  #pragma unroll
  for (int i = 0; i < 4; ++i){
    #pragma unroll
    for (int j = 0; j < 4; ++j){
      int cc = c0 + j * 16;
      #pragma unroll
      for (int e = 0; e < 4; ++e){
        int rr = r0 + i * 16 + e;
        size_t idx = (size_t)rr * N + cc;
        float v = acc[i][j][e];
        if (addsrc) v += addsrc[idx];
        Cf[idx] = v;
      }
    }
  }
}

// ---------------- dt = softplus(dtraw + dt_bias), fp32 path ----------------
__global__ __launch_bounds__(256) void dt_kernel(const float* __restrict__ dtraw,
                                                 const float* __restrict__ dt_bias,
                                                 float* __restrict__ dtb)
{
  int idx = blockIdx.x * 256 + threadIdx.x;
  float raw = dtraw[idx] + dt_bias[idx & 63];
  dtb[idx] = (raw > 20.f) ? raw : log1pf(expf(raw));
}

// ---------------- per (b,h,c) inclusive cumsum of dA = dt*A within chunk ----------------
__global__ __launch_bounds__(64) void acum_kernel(const float* __restrict__ dtb,
                                                  const float* __restrict__ A_log,
                                                  float* __restrict__ acum)
{
  int bid = blockIdx.x;          // (b*NH + h)*NCH + c
  int c = bid & 15;
  int hh = (bid >> 4) & 63;
  int b = bid >> 10;
  int lane = threadIdx.x;
  float Av = -expf(A_log[hh]);
  int rowbase = b * LTOT + c * CHUNK_;
  float v0 = dtb[(size_t)(rowbase + 2 * lane) * NH + hh] * Av;
  float v1 = dtb[(size_t)(rowbase + 2 * lane + 1) * NH + hh] * Av;
  float s = v0 + v1;
  #pragma unroll
  for (int d = 1; d < 64; d <<= 1){
    float t = __shfl_up(s, d, 64);
    if (lane >= d) s += t;
  }
  float excl = s - (v0 + v1);
  float* dst = acum + ((size_t)(b * NH + hh)) * LTOT + c * CHUNK_;
  dst[2 * lane]     = excl + v0;
  dst[2 * lane + 1] = excl + v0 + v1;
}

// ---------------- depthwise causal conv (width 4) + bias + SiLU; 4 l's per thread ----------------
__global__ __launch_bounds__(256) void conv_kernel(const unsigned short* __restrict__ xdt,
                                                   const float* __restrict__ cw,
                                                   const float* __restrict__ cb,
                                                   unsigned short* __restrict__ xbc)
{
  int ch = blockIdx.x * 256 + threadIdx.x;   // 17*256 = 4352 = CONVD exactly
  int l0 = blockIdx.y * 4, b = blockIdx.z;
  float x[7];
  #pragma unroll
  for (int j = 0; j < 7; j++){
    int ls = l0 - 3 + j;
    x[j] = (ls >= 0) ? b2f(xdt[((size_t)(b * LTOT + ls)) * XDTC + ch]) : 0.f;
  }
  float w0 = cw[ch * 4 + 0], w1 = cw[ch * 4 + 1], w2 = cw[ch * 4 + 2], w3 = cw[ch * 4 + 3];
  float bias = cb[ch];
  #pragma unroll
  for (int i = 0; i < 4; i++){
    float acc = bias + x[i] * w0 + x[i + 1] * w1 + x[i + 2] * w2 + x[i + 3] * w3;
    acc = acc / (1.f + expf(-acc));
    xbc[((size_t)(b * LTOT + l0 + i)) * CONVD + ch] = f2b(acc);
  }
}

// ---------------- SSD part 1: S' = (C·B^T)⊙L, Y_diag = S'·(x·dt)^T ----------------
__global__ __launch_bounds__(256) void ssd_sy_kernel(const unsigned short* __restrict__ xbc,
                                                     const float* __restrict__ dtb,
                                                     const float* __restrict__ acum,
                                                     float* __restrict__ y)
{
  int hh = blockIdx.x;
  int c = blockIdx.y >> 1;
  int half = blockIdx.y & 1;
  int b = blockIdx.z;
  __shared__ unsigned short Cs[64][136];    // C rows (l0..l0+63), later S'
  __shared__ unsigned short Bs[128][136];   // B rows (all s), later XT (rows 0..63 = p)
  __shared__ float ac[128];
  int tid = threadIdx.x, lane = tid & 63, w = tid >> 6;
  int l0 = half * 64;
  size_t rowbase = (size_t)b * LTOT + c * CHUNK_;
  if (tid < 128) ac[tid] = acum[((size_t)(b * NH + hh)) * LTOT + c * CHUNK_ + tid];
  #pragma unroll
  for (int p = 0; p < 8; p++){
    int lr = p * 8 + (tid >> 5);
    int n4 = (tid & 31) * 4;
    *(u16x4*)&Cs[lr][n4] =
      *(const u16x4*)&xbc[(rowbase + l0 + lr) * CONVD + DINNER + DSTATE + n4];
  }
  #pragma unroll
  for (int p = 0; p < 16; p++){
    int s = p * 8 + (tid >> 5);
    int n4 = (tid & 31) * 4;
    *(u16x4*)&Bs[s][n4] = *(const u16x4*)&xbc[(rowbase + s) * CONVD + DINNER + n4];
  }
  __syncthreads();
  f32x4 accS[8] = {};
  #pragma unroll
  for (int kk = 0; kk < 4; kk++){
    bf16x8 a = *(const bf16x8*)&Cs[w * 16 + (lane & 15)][kk * 32 + (lane >> 4) * 8];
    #pragma unroll
    for (int fc = 0; fc < 8; fc++){
      bf16x8 bb = *(const bf16x8*)&Bs[fc * 16 + (lane & 15)][kk * 32 + (lane >> 4) * 8];
      accS[fc] = mfma16(a, bb, accS[fc]);
    }
  }
  __syncthreads();
  // S' into Cs
  {
    int lr = w * 16 + ((lane >> 4) << 2);
    #pragma unroll
    for (int fc = 0; fc < 8; fc++){
      int s = fc * 16 + (lane & 15);
      #pragma unroll
      for (int j = 0; j < 4; j++){
        int l = l0 + lr + j;
        float v = (s <= l) ? accS[fc][j] * expf(ac[l] - ac[s]) : 0.f;
        Cs[lr + j][s] = f2b(v);
      }
    }
  }
  // XT = (x*dt)^T into Bs rows 0..63
  #pragma unroll
  for (int p = 0; p < 8; p++){
    int lr = p * 16 + (tid >> 4);
    int p4 = (tid & 15) * 4;
    float dtl = dtb[(rowbase + lr) * NH + hh];
    u16x4 v = *(const u16x4*)&xbc[(rowbase + lr) * CONVD + hh * HD + p4];
    Bs[p4 + 0][lr] = f2b(b2f(v[0]) * dtl);
    Bs[p4 + 1][lr] = f2b(b2f(v[1]) * dtl);
    Bs[p4 + 2][lr] = f2b(b2f(v[2]) * dtl);
    Bs[p4 + 3][lr] = f2b(b2f(v[3]) * dtl);
  }
  __syncthreads();
  f32x4 accY[4] = {};
  #pragma unroll
  for (int kk = 0; kk < 4; kk++){
    bf16x8 a = *(const bf16x8*)&Cs[w * 16 + (lane & 15)][kk * 32 + (lane >> 4) * 8];
    #pragma unroll
    for (int fc = 0; fc < 4; fc++){
      bf16x8 bb = *(const bf16x8*)&Bs[fc * 16 + (lane & 15)][kk * 32 + (lane >> 4) * 8];
      accY[fc] = mfma16(a, bb, accY[fc]);
    }
  }
  {
    int lr = w * 16 + ((lane >> 4) << 2);
    #pragma unroll
    for (int fc = 0; fc < 4; fc++){
      int p = fc * 16 + (lane & 15);
      #pragma unroll
      for (int j = 0; j < 4; j++){
        y[(rowbase + l0 + lr + j) * DINNER + hh * HD + p] = accY[fc][j];
      }
    }
  }
}

// ---------------- SSD part 2: states[p][n] = sum_l (x*dt*decay)[l][p] * B[l][n] ----------------
__global__ __launch_bounds__(256) void ssd_states_kernel(const unsigned short* __restrict__ xbc,
                                                         const float* __restrict__ dtb,
                                                         const float* __restrict__ acum,
                                                         unsigned short* __restrict__ states)
{
  int hh = blockIdx.x, c = blockIdx.y, b = blockIdx.z;
  __shared__ unsigned short BsT[128][136];  // [n][l]
  __shared__ unsigned short XT[64][136];    // [p][l]
  __shared__ float ac[128];
  int tid = threadIdx.x, lane = tid & 63, w = tid >> 6;
  size_t rowbase = (size_t)b * LTOT + c * CHUNK_;
  if (tid < 128) ac[tid] = acum[((size_t)(b * NH + hh)) * LTOT + c * CHUNK_ + tid];
  #pragma unroll
  for (int p = 0; p < 16; p++){
    int l = p * 8 + (tid >> 5);
    int n4 = (tid & 31) * 4;
    u16x4 v = *(const u16x4*)&xbc[(rowbase + l) * CONVD + DINNER + n4];
    BsT[n4 + 0][l] = v[0];
    BsT[n4 + 1][l] = v[1];
    BsT[n4 + 2][l] = v[2];
    BsT[n4 + 3][l] = v[3];
  }
  #pragma unroll
  for (int p = 0; p < 8; p++){
    int l = p * 16 + (tid >> 4);
    int p4 = (tid & 15) * 4;
    float dtl = dtb[(rowbase + l) * NH + hh];
    u16x4 v = *(const u16x4*)&xbc[(rowbase + l) * CONVD + hh * HD + p4];
    XT[p4 + 0][l] = f2b(b2f(v[0]) * dtl);
    XT[p4 + 1][l] = f2b(b2f(v[1]) * dtl);
    XT[p4 + 2][l] = f2b(b2f(v[2]) * dtl);
    XT[p4 + 3][l] = f2b(b2f(v[3]) * dtl);
  }
  __syncthreads();
  float aclast = ac[127];
  f32x4 accP[8] = {};
  #pragma unroll
  for (int kk = 0; kk < 4; kk++){
    int kbase = kk * 32 + (lane >> 4) * 8;
    union { u16x4 q[2]; unsigned short u[8]; bf16x8 v; } rw, ot;
    rw.q[0] = *(const u16x4*)&XT[w * 16 + (lane & 15)][kbase];
    rw.q[1] = *(const u16x4*)&XT[w * 16 + (lane & 15)][kbase + 4];
    #pragma unroll
    for (int e = 0; e < 8; e++){
      ot.u[e] = f2b(b2f(rw.u[e]) * expf(aclast - ac[kbase + e]));
    }
    #pragma unroll
    for (int fc = 0; fc < 8; fc++){
      bf16x8 bb = *(const bf16x8*)&BsT[fc * 16 + (lane & 15)][kbase];
      accP[fc] = mfma16(ot.v, bb, accP[fc]);
    }
  }
  size_t sbase = ((size_t)((b * NCH + c) * NH + hh)) * HD * DSTATE;
  int p0 = w * 16 + ((lane >> 4) << 2);
  #pragma unroll
  for (int fc = 0; fc < 8; fc++){
    int n = fc * 16 + (lane & 15);
    #pragma unroll
    for (int j = 0; j < 4; j++){
      states[sbase + (size_t)(p0 + j) * DSTATE + n] = f2b(accP[fc][j]);
    }
  }
}

// ---------------- SSD part 3: inter-chunk scan, in-place states -> prev; j split 8x ----------------
__global__ __launch_bounds__(256) void scan_kernel(unsigned short* __restrict__ states,
                                                   const float* __restrict__ acum)
{
  int bh = blockIdx.x;           // b*NH + h
  int b = bh >> 6, hh = bh & 63;
  int jg = blockIdx.y * 4;
  int t = threadIdx.x;
  float run[4] = {0.f, 0.f, 0.f, 0.f};
  for (int c = 0; c < NCH; c++){
    float alast = acum[(size_t)bh * LTOT + c * CHUNK_ + 127];
    float dec = expf(alast);
    size_t base = ((size_t)((b * NCH + c) * NH + hh)) * (HD * DSTATE);
    #pragma unroll
    for (int j = 0; j < 4; j++){
      size_t idx = base + (size_t)(jg + j) * 256 + t;
      float sc = b2f(states[idx]);
      states[idx] = f2b(run[j]);
      run[j] = run[j] * dec + sc;
    }
  }
}

// ---------------- SSD part 4: Y_off = decay[l] * C·prev^T, plus D*x, added into y ----------------
__global__ __launch_bounds__(256) void ssd3_kernel(const unsigned short* __restrict__ xbc,
                                                   const unsigned short* __restrict__ states,
                                                   const float* __restrict__ acum,
                                                   const float* __restrict__ Dp,
                                                   float* __restrict__ y)
{
  int hh = blockIdx.x, c = blockIdx.y, b = blockIdx.z;
  __shared__ unsigned short Cs[128][136];
  __shared__ unsigned short Ps[64][136];   // prev [p][n]
  __shared__ float ac[128];
  int tid = threadIdx.x, lane = tid & 63, w = tid >> 6;
  size_t rowbase = (size_t)b * LTOT + c * CHUNK_;
  if (tid < 128) ac[tid] = acum[((size_t)(b * NH + hh)) * LTOT + c * CHUNK_ + tid];
  #pragma unroll
  for (int p = 0; p < 16; p++){
    int l = p * 8 + (tid >> 5);
    int n4 = (tid & 31) * 4;
    *(u16x4*)&Cs[l][n4] =
      *(const u16x4*)&xbc[(rowbase + l) * CONVD + DINNER + DSTATE + n4];
  }
  size_t sbase = ((size_t)((b * NCH + c) * NH + hh)) * (HD * DSTATE);
  #pragma unroll
  for (int p = 0; p < 8; p++){
    int pp = p * 8 + (tid >> 5);
    int n4 = (tid & 31) * 4;
    *(u16x4*)&Ps[pp][n4] = *(const u16x4*)&states[sbase + (size_t)pp * DSTATE + n4];
  }
  __syncthreads();
  f32x4 acc[2][4] = {};
  #pragma unroll
  for (int kk = 0; kk < 4; kk++){
    bf16x8 a0 = *(const bf16x8*)&Cs[w * 32 + (lane & 15)][kk * 32 + (lane >> 4) * 8];
    bf16x8 a1 = *(const bf16x8*)&Cs[w * 32 + 16 + (lane & 15)][kk * 32 + (lane >> 4) * 8];
    #pragma unroll
    for (int fc = 0; fc < 4; fc++){
      bf16x8 bb = *(const bf16x8*)&Ps[fc * 16 + (lane & 15)][kk * 32 + (lane >> 4) * 8];
      acc[0][fc] = mfma16(a0, bb, acc[0][fc]);
      acc[1][fc] = mfma16(a1, bb, acc[1][fc]);
    }
  }
  float dpar = Dp[hh];
  #pragma unroll
  for (int fr = 0; fr < 2; fr++){
    int lr = w * 32 + fr * 16 + ((lane >> 4) << 2);
    #pragma unroll
    for (int fc = 0; fc < 4; fc++){
      int p = fc * 16 + (lane & 15);
      #pragma unroll
      for (int j = 0; j < 4; j++){
        int l = lr + j;
        size_t yi = (rowbase + l) * DINNER + hh * HD + p;
        float xsv = b2f(xbc[(rowbase + l) * CONVD + hh * HD + p]);
        y[yi] += acc[fr][fc][j] * expf(ac[l]) + dpar * xsv;
      }
    }
  }
}

extern "C" void kernel_launch(void* const* d_in, const int* in_sizes, int n_in,
                              void* d_out, int out_size, void* d_ws, size_t ws_size,
                              hipStream_t stream)
{
  (void)in_sizes; (void)n_in; (void)out_size; (void)ws_size;
  const float* hidden    = (const float*)d_in[0];
  const float* norm1_w   = (const float*)d_in[1];
  const float* in_proj_w = (const float*)d_in[2];
  const float* conv_w    = (const float*)d_in[3];
  const float* conv_b    = (const float*)d_in[4];
  const float* dt_bias   = (const float*)d_in[5];
  const float* A_log     = (const float*)d_in[6];
  const float* D_param   = (const float*)d_in[7];
  const float* mixer_w   = (const float*)d_in[8];
  const float* out_proj_w= (const float*)d_in[9];
  const float* norm2_w   = (const float*)d_in[10];
  const float* gate_w    = (const float*)d_in[11];
  const float* up_w      = (const float*)d_in[12];
  const float* down_w    = (const float*)d_in[13];

  char* ws = (char*)d_ws;
  // Workspace layout (175,636,480 bytes), live ranges as round 9:
  unsigned short* zbuf    = (unsigned short*)(ws);                  // bf16 4096x4096 [k2..k10]
  unsigned short* WT_cat  = (unsigned short*)(ws);                  // bf16 11264x2048 [k12.5..k13]
  unsigned short* WT_down = (unsigned short*)(ws);                  // bf16 2048x5632 [k14..k15]
  unsigned short* xdt     = (unsigned short*)(ws + 33554432ull);    // bf16 4096x4416 [k2..k5]
  unsigned short* states  = (unsigned short*)(ws + 33554432ull);    // bf16 16.7M el  [k7..k9]
  unsigned short* ygn     = (unsigned short*)(ws + 33554432ull);    // bf16 4096x4096 [k10..k11]
  unsigned short* ubuf    = (unsigned short*)(ws + 46137344ull);    // bf16 4096x5632 [k13..k13.5]
  unsigned short* xbc     = (unsigned short*)(ws + 69730304ull);    // bf16 4096x4352 [k5..k9]
  unsigned short* WT_out  = (unsigned short*)(ws + 69730304ull);    // bf16 2048x4096 [k10.5..k11]
  float* dtraw            = (float*)(ws + 105381888ull);            // f32 4096x64 [k2..k3]
  float* dtb              = (float*)(ws + 106430464ull);            // f32 4096x64 [k3..k9]
  float* acum             = (float*)(ws + 107479040ull);            // f32 128x2048 [k4..k9]
  float* ybuf             = (float*)(ws + 108527616ull);            // f32 4096x4096 [k6..k10]
  unsigned short* hbuf    = (unsigned short*)(ws + 108527616ull);   // bf16 4096x2048 [k1..k2]
  unsigned short* gbuf    = (unsigned short*)(ws + 108527616ull);   // bf16 4096x5632 [k13..k15]
  unsigned short* WT_in   = (unsigned short*)(ws + 125304832ull);   // bf16 8704x2048 [k0..k2]
  unsigned short* h2      = (unsigned short*)(ws + 154664960ull);   // bf16 4096x2048 [k12..k13]
  float* h1               = (float*)d_out;                          // f32 4096x2048 [k11..k16]
  float* outp             = (float*)d_out;

  const int dynLDS9 = 98304;   // 3 x 32KB -> 1 block/CU (512 thr)
  const int dynLDS4 = 49152;   // 3 x 16KB -> 3 blocks/CU
  hipFuncSetAttribute((const void*)gemm9_kernel,
                      hipFuncAttributeMaxDynamicSharedMemorySize, dynLDS9);
  hipFuncSetAttribute((const void*)gemm4_kernel,
                      hipFuncAttributeMaxDynamicSharedMemorySize, dynLDS4);

  // 0. convert in_proj weight -> bf16 [8704][2048] (rows >= 8512 zeroed)
  wconv_kernel<<<dim3(136, 32), 256, 0, stream>>>(in_proj_w, WT_in, DMODEL, INP);
  // 1. h = rmsnorm(hidden) -> bf16
  rms_kernel<<<NTOK, 256, 0, stream>>>(hidden, norm1_w, hbuf, DMODEL);
  // 2. zxbcdt = h @ in_proj: cols<4096 -> zbuf, cols>=4096 -> xdt; dt cols fp32 -> dtraw
  gemm9_kernel<<<dim3(34, 16), 512, dynLDS9, stream>>>(hbuf, WT_in, nullptr, nullptr,
                                                       zbuf, xdt, DINNER, nullptr, dtraw,
                                                       NTOK, INP, DMODEL);
  // 3. dt = softplus(dtraw + bias)
  dt_kernel<<<NTOK * NH / 256, 256, 0, stream>>>(dtraw, dt_bias, dtb);
  // 4. per-chunk cumsum of dt*A
  acum_kernel<<<BATCH * NH * NCH, 64, 0, stream>>>(dtb, A_log, acum);
  // 5. conv + silu (4 l's per thread)
  conv_kernel<<<dim3(CONVD / 256, LTOT / 4, BATCH), 256, 0, stream>>>(xdt, conv_w, conv_b, xbc);
  // 6. SSD intra-chunk: Y_diag
  ssd_sy_kernel<<<dim3(NH, NCH * 2, BATCH), 256, 0, stream>>>(xbc, dtb, acum, ybuf);
  // 7. SSD per-chunk states
  ssd_states_kernel<<<dim3(NH, NCH, BATCH), 256, 0, stream>>>(xbc, dtb, acum, states);
  // 8. inter-chunk scan (in-place -> prev), j split 8x
  scan_kernel<<<dim3(BATCH * NH, 8), 256, 0, stream>>>(states, acum);
  // 9. SSD off-diagonal + D*x
  ssd3_kernel<<<dim3(NH, NCH, BATCH), 256, 0, stream>>>(xbc, states, acum, D_param, ybuf);
  // 10. gated rmsnorm: ygn = rmsnorm(y * silu(z))
  rms_gated_kernel<<<NTOK, 256, 0, stream>>>(ybuf, zbuf, mixer_w, ygn);
  // 10.5 convert out_proj weight (xbc region dead)
  wconv_kernel<<<dim3(32, 64), 256, 0, stream>>>(out_proj_w, WT_out, DINNER, DMODEL);
  // 11. h1 = hidden + ygn @ out_proj (into d_out); 512 blocks, 3/CU
  gemm4_kernel<<<dim3(16, 32), 256, dynLDS4, stream>>>(ygn, WT_out, hidden, h1,
                                                       NTOK, DMODEL, DINNER);
  // 12. h2 = rmsnorm(h1) -> bf16
  rms_kernel<<<NTOK, 256, 0, stream>>>(h1, norm2_w, h2, DMODEL);
  // 12.5 convert gate+up weights into concatenated WT_cat [11264][2048]
  wconv_kernel<<<dim3(88, 32), 256, 0, stream>>>(gate_w, WT_cat, DMODEL, INTER_);
  wconv_kernel<<<dim3(88, 32), 256, 0, stream>>>(up_w, WT_cat + 11534336ull, DMODEL, INTER_);
  // 13. fused gate+up GEMM: N=11264; cols<5632 -> gbuf (raw g), cols>=5632 -> ubuf (raw u)
  gemm9_kernel<<<dim3(44, 16), 512, dynLDS9, stream>>>(h2, WT_cat, nullptr, nullptr,
                                                       gbuf, ubuf, INTER_, nullptr, nullptr,
                                                       NTOK, 2 * INTER_, DMODEL);
  // 13.5 gbuf = silu(gbuf) * ubuf
  act_kernel<<<2048, 256, 0, stream>>>(gbuf, ubuf, NTOK * INTER_ / 8);
  // 14. convert down weight (WT_cat dead)
  wconv_kernel<<<dim3(32, 88), 256, 0, stream>>>(down_w, WT_down, INTER_, DMODEL);
  // 15. out = h1 + (g*u) @ down_w (in place on d_out); 512 blocks, 3/CU
  gemm4_kernel<<<dim3(16, 32), 256, dynLDS4, stream>>>(gbuf, WT_down, h1, outp,
                                                       NTOK, DMODEL, INTER_);
}

// Round 12
// 1002.129 us; speedup vs baseline: 1.1317x; 1.1317x over previous
//
#include <hip/hip_runtime.h>

#define LTOT 2048
#define BATCH 2
#define NTOK 4096
#define DMODEL 2048
#define DSTATE 128
#define NH 64
#define HD 64
#define DINNER 4096
#define CONVD 4352
#define XDTC 4416
#define INP 8512
#define INTER_ 5632
#define CHUNK_ 128
#define NCH 16
#define EPSF 1e-6f

typedef __bf16 bf16x8 __attribute__((ext_vector_type(8)));
typedef float f32x4 __attribute__((ext_vector_type(4)));
typedef unsigned short u16x4 __attribute__((ext_vector_type(4)));
typedef unsigned short u16x8 __attribute__((ext_vector_type(8)));

__device__ __forceinline__ unsigned short f2b(float f){
  unsigned int u = __builtin_bit_cast(unsigned int, f);
  u += 0x7fffu + ((u >> 16) & 1u);
  return (unsigned short)(u >> 16);
}
__device__ __forceinline__ float b2f(unsigned short h){
  return __builtin_bit_cast(float, ((unsigned int)h) << 16);
}
__device__ __forceinline__ f32x4 mfma16(bf16x8 a, bf16x8 b, f32x4 c){
  return __builtin_amdgcn_mfma_f32_16x16x32_bf16(a, b, c, 0, 0, 0);
}
// async global->LDS, 16B per lane, wave-uniform LDS base + lane*16
typedef const __attribute__((address_space(1))) void* gas_t;
typedef __attribute__((address_space(3))) void* las_t;
__device__ __forceinline__ void gload16(const void* g, void* l){
  __builtin_amdgcn_global_load_lds((gas_t)g, (las_t)l, 16, 0, 0);
}

// Swizzle (bank-audited, refcheck-verified R10/R11): LDS rows are 64B = 4 16B-groups.
// LDS(row,g) = global(row, g ^ (row&3) ^ ((row>>2)&3)); staging pre-permutes the per-lane
// global source group, reads XOR the same terms -> every bank-group 2-way (free, m136).

// ---------------- weight convert: fp32 W[K][N] -> bf16 WT[Npad][K], zero rows n>=N ----------------
__global__ __launch_bounds__(256) void wconv_kernel(const float* __restrict__ W,
                                                    unsigned short* __restrict__ WT,
                                                    int K, int N)
{
  __shared__ unsigned short t[64][72];
  int n0 = blockIdx.x * 64, k0 = blockIdx.y * 64;
  int tid = threadIdx.x;
  int kl = tid >> 4, nl4 = (tid & 15) * 4;
  #pragma unroll
  for (int it = 0; it < 4; it++){
    int kk = kl + it * 16;
    float4 v = make_float4(0.f, 0.f, 0.f, 0.f);
    if (n0 < N) v = *(const float4*)&W[(size_t)(k0 + kk) * N + n0 + nl4];
    t[nl4 + 0][kk] = f2b(v.x);
    t[nl4 + 1][kk] = f2b(v.y);
    t[nl4 + 2][kk] = f2b(v.z);
    t[nl4 + 3][kk] = f2b(v.w);
  }
  __syncthreads();
  int nr = tid >> 3, k8 = (tid & 7) * 8;
  #pragma unroll
  for (int it = 0; it < 2; it++){
    int nn = nr + it * 32;
    *(u16x8*)&WT[(size_t)(n0 + nn) * K + k0 + k8] = *(const u16x8*)&t[nn][k8];
  }
}

// ---------------- RMSNorm: fp32 in -> bf16 out ----------------
__global__ __launch_bounds__(256) void rms_kernel(const float* __restrict__ x,
                                                  const float* __restrict__ w,
                                                  unsigned short* __restrict__ out, int width)
{
  int row = blockIdx.x, tid = threadIdx.x;
  const float* xr = x + (size_t)row * width;
  unsigned short* orow = out + (size_t)row * width;
  int nv = width >> 2;
  float ss = 0.f;
  for (int i = tid; i < nv; i += 256){
    float4 v = ((const float4*)xr)[i];
    ss += v.x*v.x + v.y*v.y + v.z*v.z + v.w*v.w;
  }
  #pragma unroll
  for (int off = 32; off > 0; off >>= 1) ss += __shfl_down(ss, off, 64);
  __shared__ float red[4];
  if ((tid & 63) == 0) red[tid >> 6] = ss;
  __syncthreads();
  float tot = red[0] + red[1] + red[2] + red[3];
  float scale = rsqrtf(tot / (float)width + EPSF);
  for (int i = tid; i < nv; i += 256){
    float4 v = ((const float4*)xr)[i];
    float4 wv = ((const float4*)w)[i];
    u16x4 o = { f2b(v.x * scale * wv.x), f2b(v.y * scale * wv.y),
                f2b(v.z * scale * wv.z), f2b(v.w * scale * wv.w) };
    ((u16x4*)orow)[i] = o;
  }
}

// ---------------- Gated RMSNorm: y fp32, z bf16 -> out bf16 ----------------
__global__ __launch_bounds__(256) void rms_gated_kernel(const float* __restrict__ y,
                                                        const unsigned short* __restrict__ z,
                                                        const float* __restrict__ w,
                                                        unsigned short* __restrict__ out)
{
  int row = blockIdx.x, tid = threadIdx.x;
  const float* yr = y + (size_t)row * DINNER;
  const unsigned short* zr = z + (size_t)row * DINNER;
  unsigned short* orow = out + (size_t)row * DINNER;
  float g[16];
  float ss = 0.f;
  #pragma unroll
  for (int ii = 0; ii < 4; ii++){
    int i = tid + ii * 256;
    float4 yv = ((const float4*)yr)[i];
    u16x4 zv = ((const u16x4*)zr)[i];
    #pragma unroll
    for (int e = 0; e < 4; e++){
      float zf = b2f(zv[e]);
      float yf = (&yv.x)[e];
      float gg = yf * (zf / (1.f + expf(-zf)));
      g[ii * 4 + e] = gg;
      ss += gg * gg;
    }
  }
  #pragma unroll
  for (int off = 32; off > 0; off >>= 1) ss += __shfl_down(ss, off, 64);
  __shared__ float red[4];
  if ((tid & 63) == 0) red[tid >> 6] = ss;
  __syncthreads();
  float tot = red[0] + red[1] + red[2] + red[3];
  float scale = rsqrtf(tot / (float)DINNER + EPSF);
  #pragma unroll
  for (int ii = 0; ii < 4; ii++){
    int i = tid + ii * 256;
    float4 wv = ((const float4*)w)[i];
    u16x4 o;
    #pragma unroll
    for (int e = 0; e < 4; e++) o[e] = f2b(g[ii * 4 + e] * scale * (&wv.x)[e]);
    ((u16x4*)orow)[i] = o;
  }
}

// ---------------- SwiGLU combine: g = silu(g) * u, bf16 ----------------
__global__ __launch_bounds__(256) void act_kernel(unsigned short* __restrict__ g,
                                                  const unsigned short* __restrict__ u, int n8)
{
  int stride = gridDim.x * 256;
  for (int i = blockIdx.x * 256 + threadIdx.x; i < n8; i += stride){
    u16x8 gv = ((const u16x8*)g)[i];
    u16x8 uv = ((const u16x8*)u)[i];
    u16x8 o;
    #pragma unroll
    for (int e = 0; e < 8; e++){
      float gf = b2f(gv[e]);
      o[e] = f2b(gf / (1.f + expf(-gf)) * b2f(uv[e]));
    }
    ((u16x8*)g)[i] = o;
  }
}

// ---------------- GEMM3: 128(M)x256(N), BK=32, 8 waves, 3x24KB bufs -> 2 blocks/CU -------------
// Measured-best structure (R9: in_proj ~200us, gate+up 258us): single-phase counted-vmcnt
// pipeline, ONE barrier/tile; inter-block overlap at 2 blocks/CU hides ds_read under MFMA (m114).
// This round: 3-term swizzle (R10-verified) replaces the 2-term one.
__global__ __launch_bounds__(512, 2) void gemm3_kernel(const unsigned short* __restrict__ A,
                                                       const unsigned short* __restrict__ BT,
                                                       const float* __restrict__ addsrc,
                                                       float* __restrict__ Cf,
                                                       unsigned short* __restrict__ Cb,
                                                       unsigned short* __restrict__ Cb2, int splitN,
                                                       const unsigned short* __restrict__ gate,
                                                       float* __restrict__ dtraw,
                                                       int M, int N, int K)
{
  extern __shared__ unsigned short lds[];    // 36864 u16 = 72KB; buf i at i*12288 (A 4096, B 8192 u16)
  int tid = threadIdx.x, lane = tid & 63, w = tid >> 6;
  int wm = w >> 2, wn = w & 3;               // wave grid 2(M) x 4(N); wave block 64x64
  int bid = blockIdx.x + blockIdx.y * gridDim.x;
  int nwg = gridDim.x * gridDim.y;
  int q8 = nwg >> 3, r8 = nwg & 7;
  int xcd = bid & 7, boff = bid >> 3;
  int wgid = (xcd < r8 ? xcd * (q8 + 1) : r8 * (q8 + 1) + (xcd - r8) * q8) + boff;
  int bn = (wgid % gridDim.x) * 256;
  int bm = (wgid / gridDim.x) * 128;

  int gsrc = (((lane & 3) ^ ((lane >> 2) & 3) ^ ((4 * w + (lane >> 4)) & 3)) << 3);
  int prow_l = lane >> 2;
  int ko = (((lane >> 4) ^ (lane & 3) ^ ((lane >> 2) & 3)) << 3);
  int rsel = (lane & 15) * 32 + ko;

  f32x4 acc[4][4] = {};
  int NT = K >> 5;

  #define STAGE(kt, bsel)                                                              \
    {                                                                                  \
      unsigned short* bb_ = &lds[(bsel) * 12288];                                      \
      size_t k0_ = (size_t)(kt) << 5;                                                  \
      gload16(&A [(size_t)(bm +       w * 16 + prow_l) * K + k0_ + gsrc], &bb_[w * 512]);            \
      gload16(&BT[(size_t)(bn +       w * 16 + prow_l) * K + k0_ + gsrc], &bb_[4096 + w * 512]);     \
      gload16(&BT[(size_t)(bn + 128 + w * 16 + prow_l) * K + k0_ + gsrc], &bb_[8192 + w * 512]);     \
    }

  STAGE(0, 0)
  STAGE(1, 1)
  asm volatile("s_waitcnt vmcnt(3)" ::: "memory");
  __builtin_amdgcn_s_barrier();
  asm volatile("" ::: "memory");

  for (int t = 0; t < NT; ++t){
    const unsigned short* bufc = &lds[(t % 3) * 12288];
    bf16x8 afr[4], bfr[4];
    #pragma unroll
    for (int i = 0; i < 4; ++i)
      afr[i] = *(const bf16x8*)&bufc[(wm * 64 + i * 16) * 32 + rsel];
    #pragma unroll
    for (int c = 0; c < 4; ++c)
      bfr[c] = *(const bf16x8*)&bufc[4096 + (wn * 64 + c * 16) * 32 + rsel];
    if (t + 2 < NT) STAGE(t + 2, (t + 2) % 3)
    __builtin_amdgcn_s_setprio(1);
    #pragma unroll
    for (int i = 0; i < 4; ++i)
      #pragma unroll
      for (int c = 0; c < 4; ++c)
        acc[i][c] = mfma16(afr[i], bfr[c], acc[i][c]);
    __builtin_amdgcn_s_setprio(0);
    if (t + 2 < NT)      asm volatile("s_waitcnt vmcnt(3)" ::: "memory");  // t+1 landed
    else if (t + 1 < NT) asm volatile("s_waitcnt vmcnt(0)" ::: "memory");  // final drain
    asm volatile("" ::: "memory");
    __builtin_amdgcn_s_barrier();
    asm volatile("" ::: "memory");
  }
  #undef STAGE

  int r0 = bm + wm * 64 + ((lane >> 4) << 2);
  int c0 = bn + wn * 64 + (lane & 15);
  #pragma unroll
  for (int i = 0; i < 4; ++i){
    #pragma unroll
    for (int j = 0; j < 4; ++j){
      int cc = c0 + j * 16;
      if (cc < N){
        #pragma unroll
        for (int e = 0; e < 4; ++e){
          int rr = r0 + i * 16 + e;
          float v = acc[i][j][e];
          if (Cf){
            size_t idx = (size_t)rr * N + cc;
            if (addsrc) v += addsrc[idx];
            Cf[idx] = v;
          } else if (cc < splitN){
            size_t idx = (size_t)rr * splitN + cc;
            float vv = v;
            if (gate){ float gg = b2f(gate[idx]); vv = gg / (1.f + expf(-gg)) * v; }
            Cb[idx] = f2b(vv);
          } else {
            Cb2[(size_t)rr * (N - splitN) + (cc - splitN)] = f2b(v);
            if (dtraw && cc >= N - NH) dtraw[(size_t)rr * NH + (cc - (N - NH))] = v;
          }
        }
      }
    }
  }
}

// ---------------- GEMM4: 128(M)x128(N), BK=32, 4 waves (2x2), 3x16KB bufs -> 3 blocks/CU -------
__global__ __launch_bounds__(256, 3) void gemm4_kernel(const unsigned short* __restrict__ A,
                                                       const unsigned short* __restrict__ BT,
                                                       const float* __restrict__ addsrc,
                                                       float* __restrict__ Cf,
                                                       int M, int N, int K)
{
  extern __shared__ unsigned short lds[];    // 24576 u16 = 48KB; buf i at i*8192 (A 4096, B 4096)
  int tid = threadIdx.x, lane = tid & 63, w = tid >> 6;
  int wm = w >> 1, wn = w & 1;               // wave grid 2(M) x 2(N); wave block 64x64
  int bid = blockIdx.x + blockIdx.y * gridDim.x;
  int nwg = gridDim.x * gridDim.y;
  int q8 = nwg >> 3, r8 = nwg & 7;
  int xcd = bid & 7, boff = bid >> 3;
  int wgid = (xcd < r8 ? xcd * (q8 + 1) : r8 * (q8 + 1) + (xcd - r8) * q8) + boff;
  int bn = (wgid % gridDim.x) * 128;
  int bm = (wgid / gridDim.x) * 128;

  int gsrc = (((lane & 3) ^ ((lane >> 2) & 3) ^ ((4 * w + (lane >> 4)) & 3)) << 3);
  int prow_l = lane >> 2;
  int ko = (((lane >> 4) ^ (lane & 3) ^ ((lane >> 2) & 3)) << 3);
  int rsel = (lane & 15) * 32 + ko;

  f32x4 acc[4][4] = {};
  int NT = K >> 5;

  #define STAGE4(kt, bsel)                                                             \
    {                                                                                  \
      unsigned short* bb_ = &lds[(bsel) * 8192];                                       \
      size_t k0_ = (size_t)(kt) << 5;                                                  \
      gload16(&A [(size_t)(bm +      w * 16 + prow_l) * K + k0_ + gsrc], &bb_[w * 512]);          \
      gload16(&A [(size_t)(bm + 64 + w * 16 + prow_l) * K + k0_ + gsrc], &bb_[2048 + w * 512]);   \
      gload16(&BT[(size_t)(bn +      w * 16 + prow_l) * K + k0_ + gsrc], &bb_[4096 + w * 512]);   \
      gload16(&BT[(size_t)(bn + 64 + w * 16 + prow_l) * K + k0_ + gsrc], &bb_[6144 + w * 512]);   \
    }

  STAGE4(0, 0)
  STAGE4(1, 1)
  asm volatile("s_waitcnt vmcnt(4)" ::: "memory");
  __builtin_amdgcn_s_barrier();
  asm volatile("" ::: "memory");

  for (int t = 0; t < NT; ++t){
    const unsigned short* bufc = &lds[(t % 3) * 8192];
    bf16x8 afr[4], bfr[4];
    #pragma unroll
    for (int i = 0; i < 4; ++i)
      afr[i] = *(const bf16x8*)&bufc[(wm * 64 + i * 16) * 32 + rsel];
    #pragma unroll
    for (int c = 0; c < 4; ++c)
      bfr[c] = *(const bf16x8*)&bufc[4096 + (wn * 64 + c * 16) * 32 + rsel];
    if (t + 2 < NT) STAGE4(t + 2, (t + 2) % 3)
    __builtin_amdgcn_s_setprio(1);
    #pragma unroll
    for (int i = 0; i < 4; ++i)
      #pragma unroll
      for (int c = 0; c < 4; ++c)
        acc[i][c] = mfma16(afr[i], bfr[c], acc[i][c]);
    __builtin_amdgcn_s_setprio(0);
    if (t + 2 < NT)      asm volatile("s_waitcnt vmcnt(4)" ::: "memory");
    else if (t + 1 < NT) asm volatile("s_waitcnt vmcnt(0)" ::: "memory");
    asm volatile("" ::: "memory");
    __builtin_amdgcn_s_barrier();
    asm volatile("" ::: "memory");
  }
  #undef STAGE4

  int r0 = bm + wm * 64 + ((lane >> 4) << 2);
  int c0 = bn + wn * 64 + (lane & 15);
  #pragma unroll
  for (int i = 0; i < 4; ++i){
    #pragma unroll
    for (int j = 0; j < 4; ++j){
      int cc = c0 + j * 16;
      #pragma unroll
      for (int e = 0; e < 4; ++e){
        int rr = r0 + i * 16 + e;
        size_t idx = (size_t)rr * N + cc;
        float v = acc[i][j][e];
        if (addsrc) v += addsrc[idx];
        Cf[idx] = v;
      }
    }
  }
}

// ---------------- dt = softplus(dtraw + dt_bias), fp32 path ----------------
__global__ __launch_bounds__(256) void dt_kernel(const float* __restrict__ dtraw,
                                                 const float* __restrict__ dt_bias,
                                                 float* __restrict__ dtb)
{
  int idx = blockIdx.x * 256 + threadIdx.x;
  float raw = dtraw[idx] + dt_bias[idx & 63];
  dtb[idx] = (raw > 20.f) ? raw : log1pf(expf(raw));
}

// ---------------- per (b,h,c) inclusive cumsum of dA = dt*A within chunk ----------------
__global__ __launch_bounds__(64) void acum_kernel(const float* __restrict__ dtb,
                                                  const float* __restrict__ A_log,
                                                  float* __restrict__ acum)
{
  int bid = blockIdx.x;          // (b*NH + h)*NCH + c
  int c = bid & 15;
  int hh = (bid >> 4) & 63;
  int b = bid >> 10;
  int lane = threadIdx.x;
  float Av = -expf(A_log[hh]);
  int rowbase = b * LTOT + c * CHUNK_;
  float v0 = dtb[(size_t)(rowbase + 2 * lane) * NH + hh] * Av;
  float v1 = dtb[(size_t)(rowbase + 2 * lane + 1) * NH + hh] * Av;
  float s = v0 + v1;
  #pragma unroll
  for (int d = 1; d < 64; d <<= 1){
    float t = __shfl_up(s, d, 64);
    if (lane >= d) s += t;
  }
  float excl = s - (v0 + v1);
  float* dst = acum + ((size_t)(b * NH + hh)) * LTOT + c * CHUNK_;
  dst[2 * lane]     = excl + v0;
  dst[2 * lane + 1] = excl + v0 + v1;
}

// ---------------- depthwise causal conv (width 4) + bias + SiLU; 4 l's per thread ----------------
__global__ __launch_bounds__(256) void conv_kernel(const unsigned short* __restrict__ xdt,
                                                   const float* __restrict__ cw,
                                                   const float* __restrict__ cb,
                                                   unsigned short* __restrict__ xbc)
{
  int ch = blockIdx.x * 256 + threadIdx.x;   // 17*256 = 4352 = CONVD exactly
  int l0 = blockIdx.y * 4, b = blockIdx.z;
  float x[7];
  #pragma unroll
  for (int j = 0; j < 7; j++){
    int ls = l0 - 3 + j;
    x[j] = (ls >= 0) ? b2f(xdt[((size_t)(b * LTOT + ls)) * XDTC + ch]) : 0.f;
  }
  float w0 = cw[ch * 4 + 0], w1 = cw[ch * 4 + 1], w2 = cw[ch * 4 + 2], w3 = cw[ch * 4 + 3];
  float bias = cb[ch];
  #pragma unroll
  for (int i = 0; i < 4; i++){
    float acc = bias + x[i] * w0 + x[i + 1] * w1 + x[i + 2] * w2 + x[i + 3] * w3;
    acc = acc / (1.f + expf(-acc));
    xbc[((size_t)(b * LTOT + l0 + i)) * CONVD + ch] = f2b(acc);
  }
}

// ---------------- SSD part 1: S' = (C·B^T)⊙L, Y_diag = S'·(x·dt)^T ----------------
__global__ __launch_bounds__(256) void ssd_sy_kernel(const unsigned short* __restrict__ xbc,
                                                     const float* __restrict__ dtb,
                                                     const float* __restrict__ acum,
                                                     float* __restrict__ y)
{
  int hh = blockIdx.x;
  int c = blockIdx.y >> 1;
  int half = blockIdx.y & 1;
  int b = blockIdx.z;
  __shared__ unsigned short Cs[64][136];    // C rows (l0..l0+63), later S'
  __shared__ unsigned short Bs[128][136];   // B rows (all s), later XT (rows 0..63 = p)
  __shared__ float ac[128];
  int tid = threadIdx.x, lane = tid & 63, w = tid >> 6;
  int l0 = half * 64;
  size_t rowbase = (size_t)b * LTOT + c * CHUNK_;
  if (tid < 128) ac[tid] = acum[((size_t)(b * NH + hh)) * LTOT + c * CHUNK_ + tid];
  #pragma unroll
  for (int p = 0; p < 8; p++){
    int lr = p * 8 + (tid >> 5);
    int n4 = (tid & 31) * 4;
    *(u16x4*)&Cs[lr][n4] =
      *(const u16x4*)&xbc[(rowbase + l0 + lr) * CONVD + DINNER + DSTATE + n4];
  }
  #pragma unroll
  for (int p = 0; p < 16; p++){
    int s = p * 8 + (tid >> 5);
    int n4 = (tid & 31) * 4;
    *(u16x4*)&Bs[s][n4] = *(const u16x4*)&xbc[(rowbase + s) * CONVD + DINNER + n4];
  }
  __syncthreads();
  f32x4 accS[8] = {};
  #pragma unroll
  for (int kk = 0; kk < 4; kk++){
    bf16x8 a = *(const bf16x8*)&Cs[w * 16 + (lane & 15)][kk * 32 + (lane >> 4) * 8];
    #pragma unroll
    for (int fc = 0; fc < 8; fc++){
      bf16x8 bb = *(const bf16x8*)&Bs[fc * 16 + (lane & 15)][kk * 32 + (lane >> 4) * 8];
      accS[fc] = mfma16(a, bb, accS[fc]);
    }
  }
  __syncthreads();
  // S' into Cs
  {
    int lr = w * 16 + ((lane >> 4) << 2);
    #pragma unroll
    for (int fc = 0; fc < 8; fc++){
      int s = fc * 16 + (lane & 15);
      #pragma unroll
      for (int j = 0; j < 4; j++){
        int l = l0 + lr + j;
        float v = (s <= l) ? accS[fc][j] * expf(ac[l] - ac[s]) : 0.f;
        Cs[lr + j][s] = f2b(v);
      }
    }
  }
  // XT = (x*dt)^T into Bs rows 0..63
  #pragma unroll
  for (int p = 0; p < 8; p++){
    int lr = p * 16 + (tid >> 4);
    int p4 = (tid & 15) * 4;
    float dtl = dtb[(rowbase + lr) * NH + hh];
    u16x4 v = *(const u16x4*)&xbc[(rowbase + lr) * CONVD + hh * HD + p4];
    Bs[p4 + 0][lr] = f2b(b2f(v[0]) * dtl);
    Bs[p4 + 1][lr] = f2b(b2f(v[1]) * dtl);
    Bs[p4 + 2][lr] = f2b(b2f(v[2]) * dtl);
    Bs[p4 + 3][lr] = f2b(b2f(v[3]) * dtl);
  }
  __syncthreads();
  f32x4 accY[4] = {};
  #pragma unroll
  for (int kk = 0; kk < 4; kk++){
    bf16x8 a = *(const bf16x8*)&Cs[w * 16 + (lane & 15)][kk * 32 + (lane >> 4) * 8];
    #pragma unroll
    for (int fc = 0; fc < 4; fc++){
      bf16x8 bb = *(const bf16x8*)&Bs[fc * 16 + (lane & 15)][kk * 32 + (lane >> 4) * 8];
      accY[fc] = mfma16(a, bb, accY[fc]);
    }
  }
  {
    int lr = w * 16 + ((lane >> 4) << 2);
    #pragma unroll
    for (int fc = 0; fc < 4; fc++){
      int p = fc * 16 + (lane & 15);
      #pragma unroll
      for (int j = 0; j < 4; j++){
        y[(rowbase + l0 + lr + j) * DINNER + hh * HD + p] = accY[fc][j];
      }
    }
  }
}

// ---------------- SSD part 2: states[p][n] = sum_l (x*dt*decay)[l][p] * B[l][n] ----------------
__global__ __launch_bounds__(256) void ssd_states_kernel(const unsigned short* __restrict__ xbc,
                                                         const float* __restrict__ dtb,
                                                         const float* __restrict__ acum,
                                                         unsigned short* __restrict__ states)
{
  int hh = blockIdx.x, c = blockIdx.y, b = blockIdx.z;
  __shared__ unsigned short BsT[128][136];  // [n][l]
  __shared__ unsigned short XT[64][136];    // [p][l]
  __shared__ float ac[128];
  int tid = threadIdx.x, lane = tid & 63, w = tid >> 6;
  size_t rowbase = (size_t)b * LTOT + c * CHUNK_;
  if (tid < 128) ac[tid] = acum[((size_t)(b * NH + hh)) * LTOT + c * CHUNK_ + tid];
  #pragma unroll
  for (int p = 0; p < 16; p++){
    int l = p * 8 + (tid >> 5);
    int n4 = (tid & 31) * 4;
    u16x4 v = *(const u16x4*)&xbc[(rowbase + l) * CONVD + DINNER + n4];
    BsT[n4 + 0][l] = v[0];
    BsT[n4 + 1][l] = v[1];
    BsT[n4 + 2][l] = v[2];
    BsT[n4 + 3][l] = v[3];
  }
  #pragma unroll
  for (int p = 0; p < 8; p++){
    int l = p * 16 + (tid >> 4);
    int p4 = (tid & 15) * 4;
    float dtl = dtb[(rowbase + l) * NH + hh];
    u16x4 v = *(const u16x4*)&xbc[(rowbase + l) * CONVD + hh * HD + p4];
    XT[p4 + 0][l] = f2b(b2f(v[0]) * dtl);
    XT[p4 + 1][l] = f2b(b2f(v[1]) * dtl);
    XT[p4 + 2][l] = f2b(b2f(v[2]) * dtl);
    XT[p4 + 3][l] = f2b(b2f(v[3]) * dtl);
  }
  __syncthreads();
  float aclast = ac[127];
  f32x4 accP[8] = {};
  #pragma unroll
  for (int kk = 0; kk < 4; kk++){
    int kbase = kk * 32 + (lane >> 4) * 8;
    union { u16x4 q[2]; unsigned short u[8]; bf16x8 v; } rw, ot;
    rw.q[0] = *(const u16x4*)&XT[w * 16 + (lane & 15)][kbase];
    rw.q[1] = *(const u16x4*)&XT[w * 16 + (lane & 15)][kbase + 4];
    #pragma unroll
    for (int e = 0; e < 8; e++){
      ot.u[e] = f2b(b2f(rw.u[e]) * expf(aclast - ac[kbase + e]));
    }
    #pragma unroll
    for (int fc = 0; fc < 8; fc++){
      bf16x8 bb = *(const bf16x8*)&BsT[fc * 16 + (lane & 15)][kbase];
      accP[fc] = mfma16(ot.v, bb, accP[fc]);
    }
  }
  size_t sbase = ((size_t)((b * NCH + c) * NH + hh)) * HD * DSTATE;
  int p0 = w * 16 + ((lane >> 4) << 2);
  #pragma unroll
  for (int fc = 0; fc < 8; fc++){
    int n = fc * 16 + (lane & 15);
    #pragma unroll
    for (int j = 0; j < 4; j++){
      states[sbase + (size_t)(p0 + j) * DSTATE + n] = f2b(accP[fc][j]);
    }
  }
}

// ---------------- SSD part 3: inter-chunk scan, in-place states -> prev; j split 8x ----------------
__global__ __launch_bounds__(256) void scan_kernel(unsigned short* __restrict__ states,
                                                   const float* __restrict__ acum)
{
  int bh = blockIdx.x;           // b*NH + h
  int b = bh >> 6, hh = bh & 63;
  int jg = blockIdx.y * 4;
  int t = threadIdx.x;
  float run[4] = {0.f, 0.f, 0.f, 0.f};
  for (int c = 0; c < NCH; c++){
    float alast = acum[(size_t)bh * LTOT + c * CHUNK_ + 127];
    float dec = expf(alast);
    size_t base = ((size_t)((b * NCH + c) * NH + hh)) * (HD * DSTATE);
    #pragma unroll
    for (int j = 0; j < 4; j++){
      size_t idx = base + (size_t)(jg + j) * 256 + t;
      float sc = b2f(states[idx]);
      states[idx] = f2b(run[j]);
      run[j] = run[j] * dec + sc;
    }
  }
}

// ---------------- SSD part 4: Y_off = decay[l] * C·prev^T, plus D*x, added into y ----------------
__global__ __launch_bounds__(256) void ssd3_kernel(const unsigned short* __restrict__ xbc,
                                                   const unsigned short* __restrict__ states,
                                                   const float* __restrict__ acum,
                                                   const float* __restrict__ Dp,
                                                   float* __restrict__ y)
{
  int hh = blockIdx.x, c = blockIdx.y, b = blockIdx.z;
  __shared__ unsigned short Cs[128][136];
  __shared__ unsigned short Ps[64][136];   // prev [p][n]
  __shared__ float ac[128];
  int tid = threadIdx.x, lane = tid & 63, w = tid >> 6;
  size_t rowbase = (size_t)b * LTOT + c * CHUNK_;
  if (tid < 128) ac[tid] = acum[((size_t)(b * NH + hh)) * LTOT + c * CHUNK_ + tid];
  #pragma unroll
  for (int p = 0; p < 16; p++){
    int l = p * 8 + (tid >> 5);
    int n4 = (tid & 31) * 4;
    *(u16x4*)&Cs[l][n4] =
      *(const u16x4*)&xbc[(rowbase + l) * CONVD + DINNER + DSTATE + n4];
  }
  size_t sbase = ((size_t)((b * NCH + c) * NH + hh)) * (HD * DSTATE);
  #pragma unroll
  for (int p = 0; p < 8; p++){
    int pp = p * 8 + (tid >> 5);
    int n4 = (tid & 31) * 4;
    *(u16x4*)&Ps[pp][n4] = *(const u16x4*)&states[sbase + (size_t)pp * DSTATE + n4];
  }
  __syncthreads();
  f32x4 acc[2][4] = {};
  #pragma unroll
  for (int kk = 0; kk < 4; kk++){
    bf16x8 a0 = *(const bf16x8*)&Cs[w * 32 + (lane & 15)][kk * 32 + (lane >> 4) * 8];
    bf16x8 a1 = *(const bf16x8*)&Cs[w * 32 + 16 + (lane & 15)][kk * 32 + (lane >> 4) * 8];
    #pragma unroll
    for (int fc = 0; fc < 4; fc++){
      bf16x8 bb = *(const bf16x8*)&Ps[fc * 16 + (lane & 15)][kk * 32 + (lane >> 4) * 8];
      acc[0][fc] = mfma16(a0, bb, acc[0][fc]);
      acc[1][fc] = mfma16(a1, bb, acc[1][fc]);
    }
  }
  float dpar = Dp[hh];
  #pragma unroll
  for (int fr = 0; fr < 2; fr++){
    int lr = w * 32 + fr * 16 + ((lane >> 4) << 2);
    #pragma unroll
    for (int fc = 0; fc < 4; fc++){
      int p = fc * 16 + (lane & 15);
      #pragma unroll
      for (int j = 0; j < 4; j++){
        int l = lr + j;
        size_t yi = (rowbase + l) * DINNER + hh * HD + p;
        float xsv = b2f(xbc[(rowbase + l) * CONVD + hh * HD + p]);
        y[yi] += acc[fr][fc][j] * expf(ac[l]) + dpar * xsv;
      }
    }
  }
}

extern "C" void kernel_launch(void* const* d_in, const int* in_sizes, int n_in,
                              void* d_out, int out_size, void* d_ws, size_t ws_size,
                              hipStream_t stream)
{
  (void)in_sizes; (void)n_in; (void)out_size; (void)ws_size;
  const float* hidden    = (const float*)d_in[0];
  const float* norm1_w   = (const float*)d_in[1];
  const float* in_proj_w = (const float*)d_in[2];
  const float* conv_w    = (const float*)d_in[3];
  const float* conv_b    = (const float*)d_in[4];
  const float* dt_bias   = (const float*)d_in[5];
  const float* A_log     = (const float*)d_in[6];
  const float* D_param   = (const float*)d_in[7];
  const float* mixer_w   = (const float*)d_in[8];
  const float* out_proj_w= (const float*)d_in[9];
  const float* norm2_w   = (const float*)d_in[10];
  const float* gate_w    = (const float*)d_in[11];
  const float* up_w      = (const float*)d_in[12];
  const float* down_w    = (const float*)d_in[13];

  char* ws = (char*)d_ws;
  // Workspace layout (175,636,480 bytes), live ranges as round 9:
  unsigned short* zbuf    = (unsigned short*)(ws);                  // bf16 4096x4096 [k2..k10]
  unsigned short* WT_cat  = (unsigned short*)(ws);                  // bf16 11264x2048 [k12.5..k13]
  unsigned short* WT_down = (unsigned short*)(ws);                  // bf16 2048x5632 [k14..k15]
  unsigned short* xdt     = (unsigned short*)(ws + 33554432ull);    // bf16 4096x4416 [k2..k5]
  unsigned short* states  = (unsigned short*)(ws + 33554432ull);    // bf16 16.7M el  [k7..k9]
  unsigned short* ygn     = (unsigned short*)(ws + 33554432ull);    // bf16 4096x4096 [k10..k11]
  unsigned short* ubuf    = (unsigned short*)(ws + 46137344ull);    // bf16 4096x5632 [k13..k13.5]
  unsigned short* xbc     = (unsigned short*)(ws + 69730304ull);    // bf16 4096x4352 [k5..k9]
  unsigned short* WT_out  = (unsigned short*)(ws + 69730304ull);    // bf16 2048x4096 [k10.5..k11]
  float* dtraw            = (float*)(ws + 105381888ull);            // f32 4096x64 [k2..k3]
  float* dtb              = (float*)(ws + 106430464ull);            // f32 4096x64 [k3..k9]
  float* acum             = (float*)(ws + 107479040ull);            // f32 128x2048 [k4..k9]
  float* ybuf             = (float*)(ws + 108527616ull);            // f32 4096x4096 [k6..k10]
  unsigned short* hbuf    = (unsigned short*)(ws + 108527616ull);   // bf16 4096x2048 [k1..k2]
  unsigned short* gbuf    = (unsigned short*)(ws + 108527616ull);   // bf16 4096x5632 [k13..k15]
  unsigned short* WT_in   = (unsigned short*)(ws + 125304832ull);   // bf16 8704x2048 [k0..k2]
  unsigned short* h2      = (unsigned short*)(ws + 154664960ull);   // bf16 4096x2048 [k12..k13]
  float* h1               = (float*)d_out;                          // f32 4096x2048 [k11..k16]
  float* outp             = (float*)d_out;

  const int dynLDS3 = 73728;   // 3 x 24KB -> 2 blocks/CU
  const int dynLDS4 = 49152;   // 3 x 16KB -> 3 blocks/CU
  hipFuncSetAttribute((const void*)gemm3_kernel,
                      hipFuncAttributeMaxDynamicSharedMemorySize, dynLDS3);
  hipFuncSetAttribute((const void*)gemm4_kernel,
                      hipFuncAttributeMaxDynamicSharedMemorySize, dynLDS4);

  // 0. convert in_proj weight -> bf16 [8704][2048] (rows >= 8512 zeroed)
  wconv_kernel<<<dim3(136, 32), 256, 0, stream>>>(in_proj_w, WT_in, DMODEL, INP);
  // 1. h = rmsnorm(hidden) -> bf16
  rms_kernel<<<NTOK, 256, 0, stream>>>(hidden, norm1_w, hbuf, DMODEL);
  // 2. zxbcdt = h @ in_proj: cols<4096 -> zbuf, cols>=4096 -> xdt; dt cols fp32 -> dtraw
  gemm3_kernel<<<dim3(34, 32), 512, dynLDS3, stream>>>(hbuf, WT_in, nullptr, nullptr,
                                                       zbuf, xdt, DINNER, nullptr, dtraw,
                                                       NTOK, INP, DMODEL);
  // 3. dt = softplus(dtraw + bias)
  dt_kernel<<<NTOK * NH / 256, 256, 0, stream>>>(dtraw, dt_bias, dtb);
  // 4. per-chunk cumsum of dt*A
  acum_kernel<<<BATCH * NH * NCH, 64, 0, stream>>>(dtb, A_log, acum);
  // 5. conv + silu (4 l's per thread)
  conv_kernel<<<dim3(CONVD / 256, LTOT / 4, BATCH), 256, 0, stream>>>(xdt, conv_w, conv_b, xbc);
  // 6. SSD intra-chunk: Y_diag
  ssd_sy_kernel<<<dim3(NH, NCH * 2, BATCH), 256, 0, stream>>>(xbc, dtb, acum, ybuf);
  // 7. SSD per-chunk states
  ssd_states_kernel<<<dim3(NH, NCH, BATCH), 256, 0, stream>>>(xbc, dtb, acum, states);
  // 8. inter-chunk scan (in-place -> prev), j split 8x
  scan_kernel<<<dim3(BATCH * NH, 8), 256, 0, stream>>>(states, acum);
  // 9. SSD off-diagonal + D*x
  ssd3_kernel<<<dim3(NH, NCH, BATCH), 256, 0, stream>>>(xbc, states, acum, D_param, ybuf);
  // 10. gated rmsnorm: ygn = rmsnorm(y * silu(z))
  rms_gated_kernel<<<NTOK, 256, 0, stream>>>(ybuf, zbuf, mixer_w, ygn);
  // 10.5 convert out_proj weight (xbc region dead)
  wconv_kernel<<<dim3(32, 64), 256, 0, stream>>>(out_proj_w, WT_out, DINNER, DMODEL);
  // 11. h1 = hidden + ygn @ out_proj (into d_out); 512 blocks, 3/CU
  gemm4_kernel<<<dim3(16, 32), 256, dynLDS4, stream>>>(ygn, WT_out, hidden, h1,
                                                       NTOK, DMODEL, DINNER);
  // 12. h2 = rmsnorm(h1) -> bf16
  rms_kernel<<<NTOK, 256, 0, stream>>>(h1, norm2_w, h2, DMODEL);
  // 12.5 convert gate+up weights into concatenated WT_cat [11264][2048]
  wconv_kernel<<<dim3(88, 32), 256, 0, stream>>>(gate_w, WT_cat, DMODEL, INTER_);
  wconv_kernel<<<dim3(88, 32), 256, 0, stream>>>(up_w, WT_cat + 11534336ull, DMODEL, INTER_);
  // 13. fused gate+up GEMM: N=11264; cols<5632 -> gbuf (raw g), cols>=5632 -> ubuf (raw u)
  gemm3_kernel<<<dim3(44, 32), 512, dynLDS3, stream>>>(h2, WT_cat, nullptr, nullptr,
                                                       gbuf, ubuf, INTER_, nullptr, nullptr,
                                                       NTOK, 2 * INTER_, DMODEL);
  // 13.5 gbuf = silu(gbuf) * ubuf
  act_kernel<<<2048, 256, 0, stream>>>(gbuf, ubuf, NTOK * INTER_ / 8);
  // 14. convert down weight (WT_cat dead)
  wconv_kernel<<<dim3(32, 88), 256, 0, stream>>>(down_w, WT_down, INTER_, DMODEL);
  // 15. out = h1 + (g*u) @ down_w (in place on d_out); 512 blocks, 3/CU
  gemm4_kernel<<<dim3(16, 32), 256, dynLDS4, stream>>>(gbuf, WT_down, h1, outp,
                                                       NTOK, DMODEL, INTER_);
}

// Round 13
// 963.794 us; speedup vs baseline: 1.1767x; 1.0398x over previous
//
#include <hip/hip_runtime.h>

#define LTOT 2048
#define BATCH 2
#define NTOK 4096
#define DMODEL 2048
#define DSTATE 128
#define NH 64
#define HD 64
#define DINNER 4096
#define CONVD 4352
#define XDTC 4416
#define INP 8512
#define INTER_ 5632
#define CHUNK_ 128
#define NCH 16
#define EPSF 1e-6f

typedef __bf16 bf16x8 __attribute__((ext_vector_type(8)));
typedef float f32x4 __attribute__((ext_vector_type(4)));
typedef unsigned short u16x4 __attribute__((ext_vector_type(4)));
typedef unsigned short u16x8 __attribute__((ext_vector_type(8)));

__device__ __forceinline__ unsigned short f2b(float f){
  unsigned int u = __builtin_bit_cast(unsigned int, f);
  u += 0x7fffu + ((u >> 16) & 1u);
  return (unsigned short)(u >> 16);
}
__device__ __forceinline__ float b2f(unsigned short h){
  return __builtin_bit_cast(float, ((unsigned int)h) << 16);
}
__device__ __forceinline__ f32x4 mfma16(bf16x8 a, bf16x8 b, f32x4 c){
  return __builtin_amdgcn_mfma_f32_16x16x32_bf16(a, b, c, 0, 0, 0);
}
// async global->LDS, 16B per lane, wave-uniform LDS base + lane*16
typedef const __attribute__((address_space(1))) void* gas_t;
typedef __attribute__((address_space(3))) void* las_t;
__device__ __forceinline__ void gload16(const void* g, void* l){
  __builtin_amdgcn_global_load_lds((gas_t)g, (las_t)l, 16, 0, 0);
}

// ---------------- weight convert: fp32 W[K][N] -> bf16 WT[(n*rstride+roff)][K] ----------------
// rstride/roff allow building the gate/up column-interleaved concat (gate->2n, up->2n+1).
__global__ __launch_bounds__(256) void wconv_kernel(const float* __restrict__ W,
                                                    unsigned short* __restrict__ WT,
                                                    int K, int N, int rstride, int roff)
{
  __shared__ unsigned short t[64][72];
  int n0 = blockIdx.x * 64, k0 = blockIdx.y * 64;
  int tid = threadIdx.x;
  int kl = tid >> 4, nl4 = (tid & 15) * 4;
  #pragma unroll
  for (int it = 0; it < 4; it++){
    int kk = kl + it * 16;
    float4 v = make_float4(0.f, 0.f, 0.f, 0.f);
    if (n0 < N) v = *(const float4*)&W[(size_t)(k0 + kk) * N + n0 + nl4];
    t[nl4 + 0][kk] = f2b(v.x);
    t[nl4 + 1][kk] = f2b(v.y);
    t[nl4 + 2][kk] = f2b(v.z);
    t[nl4 + 3][kk] = f2b(v.w);
  }
  __syncthreads();
  int nr = tid >> 3, k8 = (tid & 7) * 8;
  #pragma unroll
  for (int it = 0; it < 2; it++){
    int nn = nr + it * 32;
    *(u16x8*)&WT[((size_t)(n0 + nn) * rstride + roff) * K + k0 + k8] = *(const u16x8*)&t[nn][k8];
  }
}

// ---------------- RMSNorm: fp32 in -> bf16 out ----------------
__global__ __launch_bounds__(256) void rms_kernel(const float* __restrict__ x,
                                                  const float* __restrict__ w,
                                                  unsigned short* __restrict__ out, int width)
{
  int row = blockIdx.x, tid = threadIdx.x;
  const float* xr = x + (size_t)row * width;
  unsigned short* orow = out + (size_t)row * width;
  int nv = width >> 2;
  float ss = 0.f;
  for (int i = tid; i < nv; i += 256){
    float4 v = ((const float4*)xr)[i];
    ss += v.x*v.x + v.y*v.y + v.z*v.z + v.w*v.w;
  }
  #pragma unroll
  for (int off = 32; off > 0; off >>= 1) ss += __shfl_down(ss, off, 64);
  __shared__ float red[4];
  if ((tid & 63) == 0) red[tid >> 6] = ss;
  __syncthreads();
  float tot = red[0] + red[1] + red[2] + red[3];
  float scale = rsqrtf(tot / (float)width + EPSF);
  for (int i = tid; i < nv; i += 256){
    float4 v = ((const float4*)xr)[i];
    float4 wv = ((const float4*)w)[i];
    u16x4 o = { f2b(v.x * scale * wv.x), f2b(v.y * scale * wv.y),
                f2b(v.z * scale * wv.z), f2b(v.w * scale * wv.w) };
    ((u16x4*)orow)[i] = o;
  }
}

// ---------------- Gated RMSNorm: y fp32, z bf16 -> out bf16 ----------------
__global__ __launch_bounds__(256) void rms_gated_kernel(const float* __restrict__ y,
                                                        const unsigned short* __restrict__ z,
                                                        const float* __restrict__ w,
                                                        unsigned short* __restrict__ out)
{
  int row = blockIdx.x, tid = threadIdx.x;
  const float* yr = y + (size_t)row * DINNER;
  const unsigned short* zr = z + (size_t)row * DINNER;
  unsigned short* orow = out + (size_t)row * DINNER;
  float g[16];
  float ss = 0.f;
  #pragma unroll
  for (int ii = 0; ii < 4; ii++){
    int i = tid + ii * 256;
    float4 yv = ((const float4*)yr)[i];
    u16x4 zv = ((const u16x4*)zr)[i];
    #pragma unroll
    for (int e = 0; e < 4; e++){
      float zf = b2f(zv[e]);
      float yf = (&yv.x)[e];
      float gg = yf * (zf / (1.f + expf(-zf)));
      g[ii * 4 + e] = gg;
      ss += gg * gg;
    }
  }
  #pragma unroll
  for (int off = 32; off > 0; off >>= 1) ss += __shfl_down(ss, off, 64);
  __shared__ float red[4];
  if ((tid & 63) == 0) red[tid >> 6] = ss;
  __syncthreads();
  float tot = red[0] + red[1] + red[2] + red[3];
  float scale = rsqrtf(tot / (float)DINNER + EPSF);
  #pragma unroll
  for (int ii = 0; ii < 4; ii++){
    int i = tid + ii * 256;
    float4 wv = ((const float4*)w)[i];
    u16x4 o;
    #pragma unroll
    for (int e = 0; e < 4; e++) o[e] = f2b(g[ii * 4 + e] * scale * (&wv.x)[e]);
    ((u16x4*)orow)[i] = o;
  }
}

// ---------------- GEMM3: 128(M)x256(N), BK=32, 8 waves, 3x24KB bufs -> 2 blocks/CU -------------
// Grouped rasterization: within each XCD's bijective chunk, walk 8 M-tiles (A-block ~4.2MB,
// L2-resident) before advancing N -> B-panel streamed once per 8-row group instead of per row.
// glu=1: column-interleaved gate/up epilogue — even cols=gate, odd=up; shfl_xor(1) pairs them
// and even lanes store silu(g)*u at col cc>>1 (kills the separate act pass + ubuf).
__global__ __launch_bounds__(512, 2) void gemm3_kernel(const unsigned short* __restrict__ A,
                                                       const unsigned short* __restrict__ BT,
                                                       const float* __restrict__ addsrc,
                                                       float* __restrict__ Cf,
                                                       unsigned short* __restrict__ Cb,
                                                       unsigned short* __restrict__ Cb2, int splitN,
                                                       int glu,
                                                       float* __restrict__ dtraw,
                                                       int M, int N, int K)
{
  extern __shared__ unsigned short lds[];    // 36864 u16 = 72KB; buf i at i*12288 (A 4096, B 8192 u16)
  int tid = threadIdx.x, lane = tid & 63, w = tid >> 6;
  int wm = w >> 2, wn = w & 3;               // wave grid 2(M) x 4(N); wave block 64x64
  int bid = blockIdx.x + blockIdx.y * gridDim.x;
  int nwg = gridDim.x * gridDim.y;
  int q8 = nwg >> 3, r8 = nwg & 7;
  int xcd = bid & 7, boff = bid >> 3;
  int wgid = (xcd < r8 ? xcd * (q8 + 1) : r8 * (q8 + 1) + (xcd - r8) * q8) + boff;
  // grouped walk: 8 M-tiles fastest within group, then N advances (gridDim.y % 8 == 0 required)
  int gsz = 8 * gridDim.x;
  int grp = wgid / gsz, rem = wgid % gsz;
  int bm = (grp * 8 + (rem & 7)) * 128;
  int bn = (rem >> 3) * 256;

  int gsrc = (((lane & 3) ^ ((lane >> 2) & 3) ^ ((4 * w + (lane >> 4)) & 3)) << 3);
  int prow_l = lane >> 2;
  int ko = (((lane >> 4) ^ (lane & 3) ^ ((lane >> 2) & 3)) << 3);
  int rsel = (lane & 15) * 32 + ko;

  f32x4 acc[4][4] = {};
  int NT = K >> 5;

  #define STAGE(kt, bsel)                                                              \
    {                                                                                  \
      unsigned short* bb_ = &lds[(bsel) * 12288];                                      \
      size_t k0_ = (size_t)(kt) << 5;                                                  \
      gload16(&A [(size_t)(bm +       w * 16 + prow_l) * K + k0_ + gsrc], &bb_[w * 512]);            \
      gload16(&BT[(size_t)(bn +       w * 16 + prow_l) * K + k0_ + gsrc], &bb_[4096 + w * 512]);     \
      gload16(&BT[(size_t)(bn + 128 + w * 16 + prow_l) * K + k0_ + gsrc], &bb_[8192 + w * 512]);     \
    }

  STAGE(0, 0)
  STAGE(1, 1)
  asm volatile("s_waitcnt vmcnt(3)" ::: "memory");
  __builtin_amdgcn_s_barrier();
  asm volatile("" ::: "memory");

  for (int t = 0; t < NT; ++t){
    const unsigned short* bufc = &lds[(t % 3) * 12288];
    bf16x8 afr[4], bfr[4];
    #pragma unroll
    for (int i = 0; i < 4; ++i)
      afr[i] = *(const bf16x8*)&bufc[(wm * 64 + i * 16) * 32 + rsel];
    #pragma unroll
    for (int c = 0; c < 4; ++c)
      bfr[c] = *(const bf16x8*)&bufc[4096 + (wn * 64 + c * 16) * 32 + rsel];
    if (t + 2 < NT) STAGE(t + 2, (t + 2) % 3)
    __builtin_amdgcn_s_setprio(1);
    #pragma unroll
    for (int i = 0; i < 4; ++i)
      #pragma unroll
      for (int c = 0; c < 4; ++c)
        acc[i][c] = mfma16(afr[i], bfr[c], acc[i][c]);
    __builtin_amdgcn_s_setprio(0);
    if (t + 2 < NT)      asm volatile("s_waitcnt vmcnt(3)" ::: "memory");  // t+1 landed
    else if (t + 1 < NT) asm volatile("s_waitcnt vmcnt(0)" ::: "memory");  // final drain
    asm volatile("" ::: "memory");
    __builtin_amdgcn_s_barrier();
    asm volatile("" ::: "memory");
  }
  #undef STAGE

  int r0 = bm + wm * 64 + ((lane >> 4) << 2);
  int c0 = bn + wn * 64 + (lane & 15);
  #pragma unroll
  for (int i = 0; i < 4; ++i){
    #pragma unroll
    for (int j = 0; j < 4; ++j){
      int cc = c0 + j * 16;
      if (glu){
        // even cols hold gate, odd hold up for the same logical output column cc>>1
        #pragma unroll
        for (int e = 0; e < 4; ++e){
          float v = acc[i][j][e];
          float pv = __shfl_xor(v, 1, 64);
          if (!(lane & 1)){
            int rr = r0 + i * 16 + e;
            float res = v / (1.f + expf(-v)) * pv;   // silu(gate)*up
            Cb[(size_t)rr * (N >> 1) + (cc >> 1)] = f2b(res);
          }
        }
      } else if (cc < N){
        #pragma unroll
        for (int e = 0; e < 4; ++e){
          int rr = r0 + i * 16 + e;
          float v = acc[i][j][e];
          if (Cf){
            size_t idx = (size_t)rr * N + cc;
            if (addsrc) v += addsrc[idx];
            Cf[idx] = v;
          } else if (cc < splitN){
            Cb[(size_t)rr * splitN + cc] = f2b(v);
          } else {
            Cb2[(size_t)rr * (N - splitN) + (cc - splitN)] = f2b(v);
            if (dtraw && cc >= N - NH) dtraw[(size_t)rr * NH + (cc - (N - NH))] = v;
          }
        }
      }
    }
  }
}

// ---------------- GEMM4: 128x128, BK=32, 4 waves, 3x16KB bufs -> 3 blocks/CU; GM=4 raster ------
__global__ __launch_bounds__(256, 3) void gemm4_kernel(const unsigned short* __restrict__ A,
                                                       const unsigned short* __restrict__ BT,
                                                       const float* __restrict__ addsrc,
                                                       float* __restrict__ Cf,
                                                       int M, int N, int K)
{
  extern __shared__ unsigned short lds[];    // 24576 u16 = 48KB; buf i at i*8192 (A 4096, B 4096)
  int tid = threadIdx.x, lane = tid & 63, w = tid >> 6;
  int wm = w >> 1, wn = w & 1;               // wave grid 2(M) x 2(N); wave block 64x64
  int bid = blockIdx.x + blockIdx.y * gridDim.x;
  int nwg = gridDim.x * gridDim.y;
  int q8 = nwg >> 3, r8 = nwg & 7;
  int xcd = bid & 7, boff = bid >> 3;
  int wgid = (xcd < r8 ? xcd * (q8 + 1) : r8 * (q8 + 1) + (xcd - r8) * q8) + boff;
  int gsz = 4 * gridDim.x;                   // GM=4 (K=4096/5632 -> A-block ~4MB)
  int grp = wgid / gsz, rem = wgid % gsz;
  int bm = (grp * 4 + (rem & 3)) * 128;
  int bn = (rem >> 2) * 128;

  int gsrc = (((lane & 3) ^ ((lane >> 2) & 3) ^ ((4 * w + (lane >> 4)) & 3)) << 3);
  int prow_l = lane >> 2;
  int ko = (((lane >> 4) ^ (lane & 3) ^ ((lane >> 2) & 3)) << 3);
  int rsel = (lane & 15) * 32 + ko;

  f32x4 acc[4][4] = {};
  int NT = K >> 5;

  #define STAGE4(kt, bsel)                                                             \
    {                                                                                  \
      unsigned short* bb_ = &lds[(bsel) * 8192];                                       \
      size_t k0_ = (size_t)(kt) << 5;                                                  \
      gload16(&A [(size_t)(bm +      w * 16 + prow_l) * K + k0_ + gsrc], &bb_[w * 512]);          \
      gload16(&A [(size_t)(bm + 64 + w * 16 + prow_l) * K + k0_ + gsrc], &bb_[2048 + w * 512]);   \
      gload16(&BT[(size_t)(bn +      w * 16 + prow_l) * K + k0_ + gsrc], &bb_[4096 + w * 512]);   \
      gload16(&BT[(size_t)(bn + 64 + w * 16 + prow_l) * K + k0_ + gsrc], &bb_[6144 + w * 512]);   \
    }

  STAGE4(0, 0)
  STAGE4(1, 1)
  asm volatile("s_waitcnt vmcnt(4)" ::: "memory");
  __builtin_amdgcn_s_barrier();
  asm volatile("" ::: "memory");

  for (int t = 0; t < NT; ++t){
    const unsigned short* bufc = &lds[(t % 3) * 8192];
    bf16x8 afr[4], bfr[4];
    #pragma unroll
    for (int i = 0; i < 4; ++i)
      afr[i] = *(const bf16x8*)&bufc[(wm * 64 + i * 16) * 32 + rsel];
    #pragma unroll
    for (int c = 0; c < 4; ++c)
      bfr[c] = *(const bf16x8*)&bufc[4096 + (wn * 64 + c * 16) * 32 + rsel];
    if (t + 2 < NT) STAGE4(t + 2, (t + 2) % 3)
    __builtin_amdgcn_s_setprio(1);
    #pragma unroll
    for (int i = 0; i < 4; ++i)
      #pragma unroll
      for (int c = 0; c < 4; ++c)
        acc[i][c] = mfma16(afr[i], bfr[c], acc[i][c]);
    __builtin_amdgcn_s_setprio(0);
    if (t + 2 < NT)      asm volatile("s_waitcnt vmcnt(4)" ::: "memory");
    else if (t + 1 < NT) asm volatile("s_waitcnt vmcnt(0)" ::: "memory");
    asm volatile("" ::: "memory");
    __builtin_amdgcn_s_barrier();
    asm volatile("" ::: "memory");
  }
  #undef STAGE4

  int r0 = bm + wm * 64 + ((lane >> 4) << 2);
  int c0 = bn + wn * 64 + (lane & 15);
  #pragma unroll
  for (int i = 0; i < 4; ++i){
    #pragma unroll
    for (int j = 0; j < 4; ++j){
      int cc = c0 + j * 16;
      #pragma unroll
      for (int e = 0; e < 4; ++e){
        int rr = r0 + i * 16 + e;
        size_t idx = (size_t)rr * N + cc;
        float v = acc[i][j][e];
        if (addsrc) v += addsrc[idx];
        Cf[idx] = v;
      }
    }
  }
}

// ---------------- fused dt-softplus + per-chunk cumsum of dA = dt*A ----------------
__global__ __launch_bounds__(64) void acum_kernel(const float* __restrict__ dtraw,
                                                  const float* __restrict__ dt_bias,
                                                  const float* __restrict__ A_log,
                                                  float* __restrict__ dtb,
                                                  float* __restrict__ acum)
{
  int bid = blockIdx.x;          // (b*NH + h)*NCH + c
  int c = bid & 15;
  int hh = (bid >> 4) & 63;
  int b = bid >> 10;
  int lane = threadIdx.x;
  float Av = -expf(A_log[hh]);
  float bias = dt_bias[hh];
  int rowbase = b * LTOT + c * CHUNK_;
  float r0 = dtraw[(size_t)(rowbase + 2 * lane) * NH + hh] + bias;
  float r1 = dtraw[(size_t)(rowbase + 2 * lane + 1) * NH + hh] + bias;
  float d0 = (r0 > 20.f) ? r0 : log1pf(expf(r0));
  float d1 = (r1 > 20.f) ? r1 : log1pf(expf(r1));
  dtb[(size_t)(rowbase + 2 * lane) * NH + hh] = d0;
  dtb[(size_t)(rowbase + 2 * lane + 1) * NH + hh] = d1;
  float v0 = d0 * Av, v1 = d1 * Av;
  float s = v0 + v1;
  #pragma unroll
  for (int d = 1; d < 64; d <<= 1){
    float t = __shfl_up(s, d, 64);
    if (lane >= d) s += t;
  }
  float excl = s - (v0 + v1);
  float* dst = acum + ((size_t)(b * NH + hh)) * LTOT + c * CHUNK_;
  dst[2 * lane]     = excl + v0;
  dst[2 * lane + 1] = excl + v0 + v1;
}

// ---------------- depthwise causal conv (width 4) + bias + SiLU; 4 l's per thread ----------------
__global__ __launch_bounds__(256) void conv_kernel(const unsigned short* __restrict__ xdt,
                                                   const float* __restrict__ cw,
                                                   const float* __restrict__ cb,
                                                   unsigned short* __restrict__ xbc)
{
  int ch = blockIdx.x * 256 + threadIdx.x;   // 17*256 = 4352 = CONVD exactly
  int l0 = blockIdx.y * 4, b = blockIdx.z;
  float x[7];
  #pragma unroll
  for (int j = 0; j < 7; j++){
    int ls = l0 - 3 + j;
    x[j] = (ls >= 0) ? b2f(xdt[((size_t)(b * LTOT + ls)) * XDTC + ch]) : 0.f;
  }
  float w0 = cw[ch * 4 + 0], w1 = cw[ch * 4 + 1], w2 = cw[ch * 4 + 2], w3 = cw[ch * 4 + 3];
  float bias = cb[ch];
  #pragma unroll
  for (int i = 0; i < 4; i++){
    float acc = bias + x[i] * w0 + x[i + 1] * w1 + x[i + 2] * w2 + x[i + 3] * w3;
    acc = acc / (1.f + expf(-acc));
    xbc[((size_t)(b * LTOT + l0 + i)) * CONVD + ch] = f2b(acc);
  }
}

// ---------------- SSD part 1: S' = (C·B^T)⊙L, Y_diag = S'·(x·dt)^T ----------------
__global__ __launch_bounds__(256) void ssd_sy_kernel(const unsigned short* __restrict__ xbc,
                                                     const float* __restrict__ dtb,
                                                     const float* __restrict__ acum,
                                                     float* __restrict__ y)
{
  int hh = blockIdx.x;
  int c = blockIdx.y >> 1;
  int half = blockIdx.y & 1;
  int b = blockIdx.z;
  __shared__ unsigned short Cs[64][136];    // C rows (l0..l0+63), later S'
  __shared__ unsigned short Bs[128][136];   // B rows (all s), later XT (rows 0..63 = p)
  __shared__ float ac[128];
  int tid = threadIdx.x, lane = tid & 63, w = tid >> 6;
  int l0 = half * 64;
  size_t rowbase = (size_t)b * LTOT + c * CHUNK_;
  if (tid < 128) ac[tid] = acum[((size_t)(b * NH + hh)) * LTOT + c * CHUNK_ + tid];
  #pragma unroll
  for (int p = 0; p < 8; p++){
    int lr = p * 8 + (tid >> 5);
    int n4 = (tid & 31) * 4;
    *(u16x4*)&Cs[lr][n4] =
      *(const u16x4*)&xbc[(rowbase + l0 + lr) * CONVD + DINNER + DSTATE + n4];
  }
  #pragma unroll
  for (int p = 0; p < 16; p++){
    int s = p * 8 + (tid >> 5);
    int n4 = (tid & 31) * 4;
    *(u16x4*)&Bs[s][n4] = *(const u16x4*)&xbc[(rowbase + s) * CONVD + DINNER + n4];
  }
  __syncthreads();
  f32x4 accS[8] = {};
  #pragma unroll
  for (int kk = 0; kk < 4; kk++){
    bf16x8 a = *(const bf16x8*)&Cs[w * 16 + (lane & 15)][kk * 32 + (lane >> 4) * 8];
    #pragma unroll
    for (int fc = 0; fc < 8; fc++){
      bf16x8 bb = *(const bf16x8*)&Bs[fc * 16 + (lane & 15)][kk * 32 + (lane >> 4) * 8];
      accS[fc] = mfma16(a, bb, accS[fc]);
    }
  }
  __syncthreads();
  // S' into Cs
  {
    int lr = w * 16 + ((lane >> 4) << 2);
    #pragma unroll
    for (int fc = 0; fc < 8; fc++){
      int s = fc * 16 + (lane & 15);
      #pragma unroll
      for (int j = 0; j < 4; j++){
        int l = l0 + lr + j;
        float v = (s <= l) ? accS[fc][j] * expf(ac[l] - ac[s]) : 0.f;
        Cs[lr + j][s] = f2b(v);
      }
    }
  }
  // XT = (x*dt)^T into Bs rows 0..63
  #pragma unroll
  for (int p = 0; p < 8; p++){
    int lr = p * 16 + (tid >> 4);
    int p4 = (tid & 15) * 4;
    float dtl = dtb[(rowbase + lr) * NH + hh];
    u16x4 v = *(const u16x4*)&xbc[(rowbase + lr) * CONVD + hh * HD + p4];
    Bs[p4 + 0][lr] = f2b(b2f(v[0]) * dtl);
    Bs[p4 + 1][lr] = f2b(b2f(v[1]) * dtl);
    Bs[p4 + 2][lr] = f2b(b2f(v[2]) * dtl);
    Bs[p4 + 3][lr] = f2b(b2f(v[3]) * dtl);
  }
  __syncthreads();
  f32x4 accY[4] = {};
  #pragma unroll
  for (int kk = 0; kk < 4; kk++){
    bf16x8 a = *(const bf16x8*)&Cs[w * 16 + (lane & 15)][kk * 32 + (lane >> 4) * 8];
    #pragma unroll
    for (int fc = 0; fc < 4; fc++){
      bf16x8 bb = *(const bf16x8*)&Bs[fc * 16 + (lane & 15)][kk * 32 + (lane >> 4) * 8];
      accY[fc] = mfma16(a, bb, accY[fc]);
    }
  }
  {
    int lr = w * 16 + ((lane >> 4) << 2);
    #pragma unroll
    for (int fc = 0; fc < 4; fc++){
      int p = fc * 16 + (lane & 15);
      #pragma unroll
      for (int j = 0; j < 4; j++){
        y[(rowbase + l0 + lr + j) * DINNER + hh * HD + p] = accY[fc][j];
      }
    }
  }
}

// ---------------- SSD part 2: states[p][n] = sum_l (x*dt*decay)[l][p] * B[l][n] ----------------
__global__ __launch_bounds__(256) void ssd_states_kernel(const unsigned short* __restrict__ xbc,
                                                         const float* __restrict__ dtb,
                                                         const float* __restrict__ acum,
                                                         unsigned short* __restrict__ states)
{
  int hh = blockIdx.x, c = blockIdx.y, b = blockIdx.z;
  __shared__ unsigned short BsT[128][136];  // [n][l]
  __shared__ unsigned short XT[64][136];    // [p][l]
  __shared__ float ac[128];
  int tid = threadIdx.x, lane = tid & 63, w = tid >> 6;
  size_t rowbase = (size_t)b * LTOT + c * CHUNK_;
  if (tid < 128) ac[tid] = acum[((size_t)(b * NH + hh)) * LTOT + c * CHUNK_ + tid];
  #pragma unroll
  for (int p = 0; p < 16; p++){
    int l = p * 8 + (tid >> 5);
    int n4 = (tid & 31) * 4;
    u16x4 v = *(const u16x4*)&xbc[(rowbase + l) * CONVD + DINNER + n4];
    BsT[n4 + 0][l] = v[0];
    BsT[n4 + 1][l] = v[1];
    BsT[n4 + 2][l] = v[2];
    BsT[n4 + 3][l] = v[3];
  }
  #pragma unroll
  for (int p = 0; p < 8; p++){
    int l = p * 16 + (tid >> 4);
    int p4 = (tid & 15) * 4;
    float dtl = dtb[(rowbase + l) * NH + hh];
    u16x4 v = *(const u16x4*)&xbc[(rowbase + l) * CONVD + hh * HD + p4];
    XT[p4 + 0][l] = f2b(b2f(v[0]) * dtl);
    XT[p4 + 1][l] = f2b(b2f(v[1]) * dtl);
    XT[p4 + 2][l] = f2b(b2f(v[2]) * dtl);
    XT[p4 + 3][l] = f2b(b2f(v[3]) * dtl);
  }
  __syncthreads();
  float aclast = ac[127];
  f32x4 accP[8] = {};
  #pragma unroll
  for (int kk = 0; kk < 4; kk++){
    int kbase = kk * 32 + (lane >> 4) * 8;
    union { u16x4 q[2]; unsigned short u[8]; bf16x8 v; } rw, ot;
    rw.q[0] = *(const u16x4*)&XT[w * 16 + (lane & 15)][kbase];
    rw.q[1] = *(const u16x4*)&XT[w * 16 + (lane & 15)][kbase + 4];
    #pragma unroll
    for (int e = 0; e < 8; e++){
      ot.u[e] = f2b(b2f(rw.u[e]) * expf(aclast - ac[kbase + e]));
    }
    #pragma unroll
    for (int fc = 0; fc < 8; fc++){
      bf16x8 bb = *(const bf16x8*)&BsT[fc * 16 + (lane & 15)][kbase];
      accP[fc] = mfma16(ot.v, bb, accP[fc]);
    }
  }
  size_t sbase = ((size_t)((b * NCH + c) * NH + hh)) * HD * DSTATE;
  int p0 = w * 16 + ((lane >> 4) << 2);
  #pragma unroll
  for (int fc = 0; fc < 8; fc++){
    int n = fc * 16 + (lane & 15);
    #pragma unroll
    for (int j = 0; j < 4; j++){
      states[sbase + (size_t)(p0 + j) * DSTATE + n] = f2b(accP[fc][j]);
    }
  }
}

// ---------------- SSD part 3: inter-chunk scan, in-place states -> prev; j split 8x ----------------
__global__ __launch_bounds__(256) void scan_kernel(unsigned short* __restrict__ states,
                                                   const float* __restrict__ acum)
{
  int bh = blockIdx.x;           // b*NH + h
  int b = bh >> 6, hh = bh & 63;
  int jg = blockIdx.y * 4;
  int t = threadIdx.x;
  float run[4] = {0.f, 0.f, 0.f, 0.f};
  for (int c = 0; c < NCH; c++){
    float alast = acum[(size_t)bh * LTOT + c * CHUNK_ + 127];
    float dec = expf(alast);
    size_t base = ((size_t)((b * NCH + c) * NH + hh)) * (HD * DSTATE);
    #pragma unroll
    for (int j = 0; j < 4; j++){
      size_t idx = base + (size_t)(jg + j) * 256 + t;
      float sc = b2f(states[idx]);
      states[idx] = f2b(run[j]);
      run[j] = run[j] * dec + sc;
    }
  }
}

// ---------------- SSD part 4: Y_off = decay[l] * C·prev^T, plus D*x, added into y ----------------
__global__ __launch_bounds__(256) void ssd3_kernel(const unsigned short* __restrict__ xbc,
                                                   const unsigned short* __restrict__ states,
                                                   const float* __restrict__ acum,
                                                   const float* __restrict__ Dp,
                                                   float* __restrict__ y)
{
  int hh = blockIdx.x, c = blockIdx.y, b = blockIdx.z;
  __shared__ unsigned short Cs[128][136];
  __shared__ unsigned short Ps[64][136];   // prev [p][n]
  __shared__ float ac[128];
  int tid = threadIdx.x, lane = tid & 63, w = tid >> 6;
  size_t rowbase = (size_t)b * LTOT + c * CHUNK_;
  if (tid < 128) ac[tid] = acum[((size_t)(b * NH + hh)) * LTOT + c * CHUNK_ + tid];
  #pragma unroll
  for (int p = 0; p < 16; p++){
    int l = p * 8 + (tid >> 5);
    int n4 = (tid & 31) * 4;
    *(u16x4*)&Cs[l][n4] =
      *(const u16x4*)&xbc[(rowbase + l) * CONVD + DINNER + DSTATE + n4];
  }
  size_t sbase = ((size_t)((b * NCH + c) * NH + hh)) * (HD * DSTATE);
  #pragma unroll
  for (int p = 0; p < 8; p++){
    int pp = p * 8 + (tid >> 5);
    int n4 = (tid & 31) * 4;
    *(u16x4*)&Ps[pp][n4] = *(const u16x4*)&states[sbase + (size_t)pp * DSTATE + n4];
  }
  __syncthreads();
  f32x4 acc[2][4] = {};
  #pragma unroll
  for (int kk = 0; kk < 4; kk++){
    bf16x8 a0 = *(const bf16x8*)&Cs[w * 32 + (lane & 15)][kk * 32 + (lane >> 4) * 8];
    bf16x8 a1 = *(const bf16x8*)&Cs[w * 32 + 16 + (lane & 15)][kk * 32 + (lane >> 4) * 8];
    #pragma unroll
    for (int fc = 0; fc < 4; fc++){
      bf16x8 bb = *(const bf16x8*)&Ps[fc * 16 + (lane & 15)][kk * 32 + (lane >> 4) * 8];
      acc[0][fc] = mfma16(a0, bb, acc[0][fc]);
      acc[1][fc] = mfma16(a1, bb, acc[1][fc]);
    }
  }
  float dpar = Dp[hh];
  #pragma unroll
  for (int fr = 0; fr < 2; fr++){
    int lr = w * 32 + fr * 16 + ((lane >> 4) << 2);
    #pragma unroll
    for (int fc = 0; fc < 4; fc++){
      int p = fc * 16 + (lane & 15);
      #pragma unroll
      for (int j = 0; j < 4; j++){
        int l = lr + j;
        size_t yi = (rowbase + l) * DINNER + hh * HD + p;
        float xsv = b2f(xbc[(rowbase + l) * CONVD + hh * HD + p]);
        y[yi] += acc[fr][fc][j] * expf(ac[l]) + dpar * xsv;
      }
    }
  }
}

extern "C" void kernel_launch(void* const* d_in, const int* in_sizes, int n_in,
                              void* d_out, int out_size, void* d_ws, size_t ws_size,
                              hipStream_t stream)
{
  (void)in_sizes; (void)n_in; (void)out_size; (void)ws_size;
  const float* hidden    = (const float*)d_in[0];
  const float* norm1_w   = (const float*)d_in[1];
  const float* in_proj_w = (const float*)d_in[2];
  const float* conv_w    = (const float*)d_in[3];
  const float* conv_b    = (const float*)d_in[4];
  const float* dt_bias   = (const float*)d_in[5];
  const float* A_log     = (const float*)d_in[6];
  const float* D_param   = (const float*)d_in[7];
  const float* mixer_w   = (const float*)d_in[8];
  const float* out_proj_w= (const float*)d_in[9];
  const float* norm2_w   = (const float*)d_in[10];
  const float* gate_w    = (const float*)d_in[11];
  const float* up_w      = (const float*)d_in[12];
  const float* down_w    = (const float*)d_in[13];

  char* ws = (char*)d_ws;
  // Workspace layout (175,636,480 bytes), live ranges as round 9 (ubuf now unused):
  unsigned short* zbuf    = (unsigned short*)(ws);                  // bf16 4096x4096 [k2..k10]
  unsigned short* WT_cat  = (unsigned short*)(ws);                  // bf16 11264x2048 interleaved [k12.5..k13]
  unsigned short* WT_down = (unsigned short*)(ws);                  // bf16 2048x5632 [k14..k15]
  unsigned short* xdt     = (unsigned short*)(ws + 33554432ull);    // bf16 4096x4416 [k2..k5]
  unsigned short* states  = (unsigned short*)(ws + 33554432ull);    // bf16 16.7M el  [k7..k9]
  unsigned short* ygn     = (unsigned short*)(ws + 33554432ull);    // bf16 4096x4096 [k10..k11]
  unsigned short* xbc     = (unsigned short*)(ws + 69730304ull);    // bf16 4096x4352 [k5..k9]
  unsigned short* WT_out  = (unsigned short*)(ws + 69730304ull);    // bf16 2048x4096 [k10.5..k11]
  float* dtraw            = (float*)(ws + 105381888ull);            // f32 4096x64 [k2..k3]
  float* dtb              = (float*)(ws + 106430464ull);            // f32 4096x64 [k3..k9]
  float* acum             = (float*)(ws + 107479040ull);            // f32 128x2048 [k4..k9]
  float* ybuf             = (float*)(ws + 108527616ull);            // f32 4096x4096 [k6..k10]
  unsigned short* hbuf    = (unsigned short*)(ws + 108527616ull);   // bf16 4096x2048 [k1..k2]
  unsigned short* gbuf    = (unsigned short*)(ws + 108527616ull);   // bf16 4096x5632 [k13..k15]
  unsigned short* WT_in   = (unsigned short*)(ws + 125304832ull);   // bf16 8704x2048 [k0..k2]
  unsigned short* h2      = (unsigned short*)(ws + 154664960ull);   // bf16 4096x2048 [k12..k13]
  float* h1               = (float*)d_out;                          // f32 4096x2048 [k11..k16]
  float* outp             = (float*)d_out;

  const int dynLDS3 = 73728;   // 3 x 24KB -> 2 blocks/CU
  const int dynLDS4 = 49152;   // 3 x 16KB -> 3 blocks/CU
  hipFuncSetAttribute((const void*)gemm3_kernel,
                      hipFuncAttributeMaxDynamicSharedMemorySize, dynLDS3);
  hipFuncSetAttribute((const void*)gemm4_kernel,
                      hipFuncAttributeMaxDynamicSharedMemorySize, dynLDS4);

  // 0. convert in_proj weight -> bf16 [8704][2048] (rows >= 8512 zeroed)
  wconv_kernel<<<dim3(136, 32), 256, 0, stream>>>(in_proj_w, WT_in, DMODEL, INP, 1, 0);
  // 1. h = rmsnorm(hidden) -> bf16
  rms_kernel<<<NTOK, 256, 0, stream>>>(hidden, norm1_w, hbuf, DMODEL);
  // 2. zxbcdt = h @ in_proj: cols<4096 -> zbuf, cols>=4096 -> xdt; dt cols fp32 -> dtraw
  gemm3_kernel<<<dim3(34, 32), 512, dynLDS3, stream>>>(hbuf, WT_in, nullptr, nullptr,
                                                       zbuf, xdt, DINNER, 0, dtraw,
                                                       NTOK, INP, DMODEL);
  // 3+4. dt = softplus(dtraw+bias); per-chunk cumsum of dt*A  (fused)
  acum_kernel<<<BATCH * NH * NCH, 64, 0, stream>>>(dtraw, dt_bias, A_log, dtb, acum);
  // 5. conv + silu (4 l's per thread)
  conv_kernel<<<dim3(CONVD / 256, LTOT / 4, BATCH), 256, 0, stream>>>(xdt, conv_w, conv_b, xbc);
  // 6. SSD intra-chunk: Y_diag
  ssd_sy_kernel<<<dim3(NH, NCH * 2, BATCH), 256, 0, stream>>>(xbc, dtb, acum, ybuf);
  // 7. SSD per-chunk states
  ssd_states_kernel<<<dim3(NH, NCH, BATCH), 256, 0, stream>>>(xbc, dtb, acum, states);
  // 8. inter-chunk scan (in-place -> prev), j split 8x
  scan_kernel<<<dim3(BATCH * NH, 8), 256, 0, stream>>>(states, acum);
  // 9. SSD off-diagonal + D*x
  ssd3_kernel<<<dim3(NH, NCH, BATCH), 256, 0, stream>>>(xbc, states, acum, D_param, ybuf);
  // 10. gated rmsnorm: ygn = rmsnorm(y * silu(z))
  rms_gated_kernel<<<NTOK, 256, 0, stream>>>(ybuf, zbuf, mixer_w, ygn);
  // 10.5 convert out_proj weight (xbc region dead)
  wconv_kernel<<<dim3(32, 64), 256, 0, stream>>>(out_proj_w, WT_out, DINNER, DMODEL, 1, 0);
  // 11. h1 = hidden + ygn @ out_proj (into d_out); 512 blocks, 3/CU
  gemm4_kernel<<<dim3(16, 32), 256, dynLDS4, stream>>>(ygn, WT_out, hidden, h1,
                                                       NTOK, DMODEL, DINNER);
  // 12. h2 = rmsnorm(h1) -> bf16
  rms_kernel<<<NTOK, 256, 0, stream>>>(h1, norm2_w, h2, DMODEL);
  // 12.5 convert gate+up weights, column-interleaved: gate -> rows 2n, up -> rows 2n+1
  wconv_kernel<<<dim3(88, 32), 256, 0, stream>>>(gate_w, WT_cat, DMODEL, INTER_, 2, 0);
  wconv_kernel<<<dim3(88, 32), 256, 0, stream>>>(up_w, WT_cat, DMODEL, INTER_, 2, 1);
  // 13. fused gate+up GEMM with GLU epilogue: gbuf = silu(g)*u directly (no act pass, no ubuf)
  gemm3_kernel<<<dim3(44, 32), 512, dynLDS3, stream>>>(h2, WT_cat, nullptr, nullptr,
                                                       gbuf, nullptr, 0, 1, nullptr,
                                                       NTOK, 2 * INTER_, DMODEL);
  // 14. convert down weight (WT_cat dead)
  wconv_kernel<<<dim3(32, 88), 256, 0, stream>>>(down_w, WT_down, INTER_, DMODEL, 1, 0);
  // 15. out = h1 + (g*u) @ down_w (in place on d_out); 512 blocks, 3/CU
  gemm4_kernel<<<dim3(16, 32), 256, dynLDS4, stream>>>(gbuf, WT_down, h1, outp,
                                                       NTOK, DMODEL, INTER_);
}

// Round 14
// 919.902 us; speedup vs baseline: 1.2329x; 1.0477x over previous
//
#include <hip/hip_runtime.h>

#define LTOT 2048
#define BATCH 2
#define NTOK 4096
#define DMODEL 2048
#define DSTATE 128
#define NH 64
#define HD 64
#define DINNER 4096
#define CONVD 4352
#define XDTC 4416
#define INP 8512
#define INTER_ 5632
#define CHUNK_ 128
#define NCH 16
#define EPSF 1e-6f

typedef __bf16 bf16x8 __attribute__((ext_vector_type(8)));
typedef float f32x4 __attribute__((ext_vector_type(4)));
typedef unsigned short u16x4 __attribute__((ext_vector_type(4)));
typedef unsigned short u16x8 __attribute__((ext_vector_type(8)));

__device__ __forceinline__ unsigned short f2b(float f){
  unsigned int u = __builtin_bit_cast(unsigned int, f);
  u += 0x7fffu + ((u >> 16) & 1u);
  return (unsigned short)(u >> 16);
}
__device__ __forceinline__ float b2f(unsigned short h){
  return __builtin_bit_cast(float, ((unsigned int)h) << 16);
}
__device__ __forceinline__ f32x4 mfma16(bf16x8 a, bf16x8 b, f32x4 c){
  return __builtin_amdgcn_mfma_f32_16x16x32_bf16(a, b, c, 0, 0, 0);
}
// async global->LDS, 16B per lane, wave-uniform LDS base + lane*16
typedef const __attribute__((address_space(1))) void* gas_t;
typedef __attribute__((address_space(3))) void* las_t;
__device__ __forceinline__ void gload16(const void* g, void* l){
  __builtin_amdgcn_global_load_lds((gas_t)g, (las_t)l, 16, 0, 0);
}

// ---------------- weight convert: fp32 W[K][N] -> bf16 WT[(n*rstride+roff)][K] ----------------
__global__ __launch_bounds__(256) void wconv_kernel(const float* __restrict__ W,
                                                    unsigned short* __restrict__ WT,
                                                    int K, int N, int rstride, int roff)
{
  __shared__ unsigned short t[64][72];
  int n0 = blockIdx.x * 64, k0 = blockIdx.y * 64;
  int tid = threadIdx.x;
  int kl = tid >> 4, nl4 = (tid & 15) * 4;
  #pragma unroll
  for (int it = 0; it < 4; it++){
    int kk = kl + it * 16;
    float4 v = make_float4(0.f, 0.f, 0.f, 0.f);
    if (n0 < N) v = *(const float4*)&W[(size_t)(k0 + kk) * N + n0 + nl4];
    t[nl4 + 0][kk] = f2b(v.x);
    t[nl4 + 1][kk] = f2b(v.y);
    t[nl4 + 2][kk] = f2b(v.z);
    t[nl4 + 3][kk] = f2b(v.w);
  }
  __syncthreads();
  int nr = tid >> 3, k8 = (tid & 7) * 8;
  #pragma unroll
  for (int it = 0; it < 2; it++){
    int nn = nr + it * 32;
    *(u16x8*)&WT[((size_t)(n0 + nn) * rstride + roff) * K + k0 + k8] = *(const u16x8*)&t[nn][k8];
  }
}

// ---------------- RMSNorm: fp32 in -> bf16 out ----------------
__global__ __launch_bounds__(256) void rms_kernel(const float* __restrict__ x,
                                                  const float* __restrict__ w,
                                                  unsigned short* __restrict__ out, int width)
{
  int row = blockIdx.x, tid = threadIdx.x;
  const float* xr = x + (size_t)row * width;
  unsigned short* orow = out + (size_t)row * width;
  int nv = width >> 2;
  float ss = 0.f;
  for (int i = tid; i < nv; i += 256){
    float4 v = ((const float4*)xr)[i];
    ss += v.x*v.x + v.y*v.y + v.z*v.z + v.w*v.w;
  }
  #pragma unroll
  for (int off = 32; off > 0; off >>= 1) ss += __shfl_down(ss, off, 64);
  __shared__ float red[4];
  if ((tid & 63) == 0) red[tid >> 6] = ss;
  __syncthreads();
  float tot = red[0] + red[1] + red[2] + red[3];
  float scale = rsqrtf(tot / (float)width + EPSF);
  for (int i = tid; i < nv; i += 256){
    float4 v = ((const float4*)xr)[i];
    float4 wv = ((const float4*)w)[i];
    u16x4 o = { f2b(v.x * scale * wv.x), f2b(v.y * scale * wv.y),
                f2b(v.z * scale * wv.z), f2b(v.w * scale * wv.w) };
    ((u16x4*)orow)[i] = o;
  }
}

// ---------------- Gated RMSNorm: y bf16, z bf16 -> out bf16 ----------------
__global__ __launch_bounds__(256) void rms_gated_kernel(const unsigned short* __restrict__ y,
                                                        const unsigned short* __restrict__ z,
                                                        const float* __restrict__ w,
                                                        unsigned short* __restrict__ out)
{
  int row = blockIdx.x, tid = threadIdx.x;
  const unsigned short* yr = y + (size_t)row * DINNER;
  const unsigned short* zr = z + (size_t)row * DINNER;
  unsigned short* orow = out + (size_t)row * DINNER;
  float g[16];
  float ss = 0.f;
  #pragma unroll
  for (int ii = 0; ii < 4; ii++){
    int i = tid + ii * 256;
    u16x4 yv = ((const u16x4*)yr)[i];
    u16x4 zv = ((const u16x4*)zr)[i];
    #pragma unroll
    for (int e = 0; e < 4; e++){
      float zf = b2f(zv[e]);
      float yf = b2f(yv[e]);
      float gg = yf * (zf / (1.f + expf(-zf)));
      g[ii * 4 + e] = gg;
      ss += gg * gg;
    }
  }
  #pragma unroll
  for (int off = 32; off > 0; off >>= 1) ss += __shfl_down(ss, off, 64);
  __shared__ float red[4];
  if ((tid & 63) == 0) red[tid >> 6] = ss;
  __syncthreads();
  float tot = red[0] + red[1] + red[2] + red[3];
  float scale = rsqrtf(tot / (float)DINNER + EPSF);
  #pragma unroll
  for (int ii = 0; ii < 4; ii++){
    int i = tid + ii * 256;
    float4 wv = ((const float4*)w)[i];
    u16x4 o;
    #pragma unroll
    for (int e = 0; e < 4; e++) o[e] = f2b(g[ii * 4 + e] * scale * (&wv.x)[e]);
    ((u16x4*)orow)[i] = o;
  }
}

// ---------------- GEMM3: 128(M)x256(N), BK=32, 8 waves, 3x24KB bufs -> 2 blocks/CU -------------
// Grouped raster (8 M-tiles/group, verified R13: FETCH -75%); glu=1: interleaved gate/up GLU
// epilogue via shfl_xor (verified R13).
__global__ __launch_bounds__(512, 2) void gemm3_kernel(const unsigned short* __restrict__ A,
                                                       const unsigned short* __restrict__ BT,
                                                       const float* __restrict__ addsrc,
                                                       float* __restrict__ Cf,
                                                       unsigned short* __restrict__ Cb,
                                                       unsigned short* __restrict__ Cb2, int splitN,
                                                       int glu,
                                                       float* __restrict__ dtraw,
                                                       int M, int N, int K)
{
  extern __shared__ unsigned short lds[];
  int tid = threadIdx.x, lane = tid & 63, w = tid >> 6;
  int wm = w >> 2, wn = w & 3;
  int bid = blockIdx.x + blockIdx.y * gridDim.x;
  int nwg = gridDim.x * gridDim.y;
  int q8 = nwg >> 3, r8 = nwg & 7;
  int xcd = bid & 7, boff = bid >> 3;
  int wgid = (xcd < r8 ? xcd * (q8 + 1) : r8 * (q8 + 1) + (xcd - r8) * q8) + boff;
  int gsz = 8 * gridDim.x;
  int grp = wgid / gsz, rem = wgid % gsz;
  int bm = (grp * 8 + (rem & 7)) * 128;
  int bn = (rem >> 3) * 256;

  int gsrc = (((lane & 3) ^ ((lane >> 2) & 3) ^ ((4 * w + (lane >> 4)) & 3)) << 3);
  int prow_l = lane >> 2;
  int ko = (((lane >> 4) ^ (lane & 3) ^ ((lane >> 2) & 3)) << 3);
  int rsel = (lane & 15) * 32 + ko;

  f32x4 acc[4][4] = {};
  int NT = K >> 5;

  #define STAGE(kt, bsel)                                                              \
    {                                                                                  \
      unsigned short* bb_ = &lds[(bsel) * 12288];                                      \
      size_t k0_ = (size_t)(kt) << 5;                                                  \
      gload16(&A [(size_t)(bm +       w * 16 + prow_l) * K + k0_ + gsrc], &bb_[w * 512]);            \
      gload16(&BT[(size_t)(bn +       w * 16 + prow_l) * K + k0_ + gsrc], &bb_[4096 + w * 512]);     \
      gload16(&BT[(size_t)(bn + 128 + w * 16 + prow_l) * K + k0_ + gsrc], &bb_[8192 + w * 512]);     \
    }

  STAGE(0, 0)
  STAGE(1, 1)
  asm volatile("s_waitcnt vmcnt(3)" ::: "memory");
  __builtin_amdgcn_s_barrier();
  asm volatile("" ::: "memory");

  for (int t = 0; t < NT; ++t){
    const unsigned short* bufc = &lds[(t % 3) * 12288];
    bf16x8 afr[4], bfr[4];
    #pragma unroll
    for (int i = 0; i < 4; ++i)
      afr[i] = *(const bf16x8*)&bufc[(wm * 64 + i * 16) * 32 + rsel];
    #pragma unroll
    for (int c = 0; c < 4; ++c)
      bfr[c] = *(const bf16x8*)&bufc[4096 + (wn * 64 + c * 16) * 32 + rsel];
    if (t + 2 < NT) STAGE(t + 2, (t + 2) % 3)
    __builtin_amdgcn_s_setprio(1);
    #pragma unroll
    for (int i = 0; i < 4; ++i)
      #pragma unroll
      for (int c = 0; c < 4; ++c)
        acc[i][c] = mfma16(afr[i], bfr[c], acc[i][c]);
    __builtin_amdgcn_s_setprio(0);
    if (t + 2 < NT)      asm volatile("s_waitcnt vmcnt(3)" ::: "memory");
    else if (t + 1 < NT) asm volatile("s_waitcnt vmcnt(0)" ::: "memory");
    asm volatile("" ::: "memory");
    __builtin_amdgcn_s_barrier();
    asm volatile("" ::: "memory");
  }
  #undef STAGE

  int r0 = bm + wm * 64 + ((lane >> 4) << 2);
  int c0 = bn + wn * 64 + (lane & 15);
  #pragma unroll
  for (int i = 0; i < 4; ++i){
    #pragma unroll
    for (int j = 0; j < 4; ++j){
      int cc = c0 + j * 16;
      if (glu){
        #pragma unroll
        for (int e = 0; e < 4; ++e){
          float v = acc[i][j][e];
          float pv = __shfl_xor(v, 1, 64);
          if (!(lane & 1)){
            int rr = r0 + i * 16 + e;
            float res = v / (1.f + expf(-v)) * pv;   // silu(gate)*up
            Cb[(size_t)rr * (N >> 1) + (cc >> 1)] = f2b(res);
          }
        }
      } else if (cc < N){
        #pragma unroll
        for (int e = 0; e < 4; ++e){
          int rr = r0 + i * 16 + e;
          float v = acc[i][j][e];
          if (Cf){
            size_t idx = (size_t)rr * N + cc;
            if (addsrc) v += addsrc[idx];
            Cf[idx] = v;
          } else if (cc < splitN){
            Cb[(size_t)rr * splitN + cc] = f2b(v);
          } else {
            Cb2[(size_t)rr * (N - splitN) + (cc - splitN)] = f2b(v);
            if (dtraw && cc >= N - NH) dtraw[(size_t)rr * NH + (cc - (N - NH))] = v;
          }
        }
      }
    }
  }
}

// ---------------- GEMM4: 128x128, BK=32, 4 waves, 3x16KB bufs -> 3 blocks/CU; GM=4 raster ------
__global__ __launch_bounds__(256, 3) void gemm4_kernel(const unsigned short* __restrict__ A,
                                                       const unsigned short* __restrict__ BT,
                                                       const float* __restrict__ addsrc,
                                                       float* __restrict__ Cf,
                                                       int M, int N, int K)
{
  extern __shared__ unsigned short lds[];
  int tid = threadIdx.x, lane = tid & 63, w = tid >> 6;
  int wm = w >> 1, wn = w & 1;
  int bid = blockIdx.x + blockIdx.y * gridDim.x;
  int nwg = gridDim.x * gridDim.y;
  int q8 = nwg >> 3, r8 = nwg & 7;
  int xcd = bid & 7, boff = bid >> 3;
  int wgid = (xcd < r8 ? xcd * (q8 + 1) : r8 * (q8 + 1) + (xcd - r8) * q8) + boff;
  int gsz = 4 * gridDim.x;
  int grp = wgid / gsz, rem = wgid % gsz;
  int bm = (grp * 4 + (rem & 3)) * 128;
  int bn = (rem >> 2) * 128;

  int gsrc = (((lane & 3) ^ ((lane >> 2) & 3) ^ ((4 * w + (lane >> 4)) & 3)) << 3);
  int prow_l = lane >> 2;
  int ko = (((lane >> 4) ^ (lane & 3) ^ ((lane >> 2) & 3)) << 3);
  int rsel = (lane & 15) * 32 + ko;

  f32x4 acc[4][4] = {};
  int NT = K >> 5;

  #define STAGE4(kt, bsel)                                                             \
    {                                                                                  \
      unsigned short* bb_ = &lds[(bsel) * 8192];                                       \
      size_t k0_ = (size_t)(kt) << 5;                                                  \
      gload16(&A [(size_t)(bm +      w * 16 + prow_l) * K + k0_ + gsrc], &bb_[w * 512]);          \
      gload16(&A [(size_t)(bm + 64 + w * 16 + prow_l) * K + k0_ + gsrc], &bb_[2048 + w * 512]);   \
      gload16(&BT[(size_t)(bn +      w * 16 + prow_l) * K + k0_ + gsrc], &bb_[4096 + w * 512]);   \
      gload16(&BT[(size_t)(bn + 64 + w * 16 + prow_l) * K + k0_ + gsrc], &bb_[6144 + w * 512]);   \
    }

  STAGE4(0, 0)
  STAGE4(1, 1)
  asm volatile("s_waitcnt vmcnt(4)" ::: "memory");
  __builtin_amdgcn_s_barrier();
  asm volatile("" ::: "memory");

  for (int t = 0; t < NT; ++t){
    const unsigned short* bufc = &lds[(t % 3) * 8192];
    bf16x8 afr[4], bfr[4];
    #pragma unroll
    for (int i = 0; i < 4; ++i)
      afr[i] = *(const bf16x8*)&bufc[(wm * 64 + i * 16) * 32 + rsel];
    #pragma unroll
    for (int c = 0; c < 4; ++c)
      bfr[c] = *(const bf16x8*)&bufc[4096 + (wn * 64 + c * 16) * 32 + rsel];
    if (t + 2 < NT) STAGE4(t + 2, (t + 2) % 3)
    __builtin_amdgcn_s_setprio(1);
    #pragma unroll
    for (int i = 0; i < 4; ++i)
      #pragma unroll
      for (int c = 0; c < 4; ++c)
        acc[i][c] = mfma16(afr[i], bfr[c], acc[i][c]);
    __builtin_amdgcn_s_setprio(0);
    if (t + 2 < NT)      asm volatile("s_waitcnt vmcnt(4)" ::: "memory");
    else if (t + 1 < NT) asm volatile("s_waitcnt vmcnt(0)" ::: "memory");
    asm volatile("" ::: "memory");
    __builtin_amdgcn_s_barrier();
    asm volatile("" ::: "memory");
  }
  #undef STAGE4

  int r0 = bm + wm * 64 + ((lane >> 4) << 2);
  int c0 = bn + wn * 64 + (lane & 15);
  #pragma unroll
  for (int i = 0; i < 4; ++i){
    #pragma unroll
    for (int j = 0; j < 4; ++j){
      int cc = c0 + j * 16;
      #pragma unroll
      for (int e = 0; e < 4; ++e){
        int rr = r0 + i * 16 + e;
        size_t idx = (size_t)rr * N + cc;
        float v = acc[i][j][e];
        if (addsrc) v += addsrc[idx];
        Cf[idx] = v;
      }
    }
  }
}

// ---------------- fused dt-softplus + per-chunk cumsum of dA = dt*A ----------------
__global__ __launch_bounds__(64) void acum_kernel(const float* __restrict__ dtraw,
                                                  const float* __restrict__ dt_bias,
                                                  const float* __restrict__ A_log,
                                                  float* __restrict__ dtb,
                                                  float* __restrict__ acum)
{
  int bid = blockIdx.x;
  int c = bid & 15;
  int hh = (bid >> 4) & 63;
  int b = bid >> 10;
  int lane = threadIdx.x;
  float Av = -expf(A_log[hh]);
  float bias = dt_bias[hh];
  int rowbase = b * LTOT + c * CHUNK_;
  float r0 = dtraw[(size_t)(rowbase + 2 * lane) * NH + hh] + bias;
  float r1 = dtraw[(size_t)(rowbase + 2 * lane + 1) * NH + hh] + bias;
  float d0 = (r0 > 20.f) ? r0 : log1pf(expf(r0));
  float d1 = (r1 > 20.f) ? r1 : log1pf(expf(r1));
  dtb[(size_t)(rowbase + 2 * lane) * NH + hh] = d0;
  dtb[(size_t)(rowbase + 2 * lane + 1) * NH + hh] = d1;
  float v0 = d0 * Av, v1 = d1 * Av;
  float s = v0 + v1;
  #pragma unroll
  for (int d = 1; d < 64; d <<= 1){
    float t = __shfl_up(s, d, 64);
    if (lane >= d) s += t;
  }
  float excl = s - (v0 + v1);
  float* dst = acum + ((size_t)(b * NH + hh)) * LTOT + c * CHUNK_;
  dst[2 * lane]     = excl + v0;
  dst[2 * lane + 1] = excl + v0 + v1;
}

// ---------------- depthwise causal conv (width 4) + bias + SiLU; 4 l's per thread ----------------
__global__ __launch_bounds__(256) void conv_kernel(const unsigned short* __restrict__ xdt,
                                                   const float* __restrict__ cw,
                                                   const float* __restrict__ cb,
                                                   unsigned short* __restrict__ xbc)
{
  int ch = blockIdx.x * 256 + threadIdx.x;
  int l0 = blockIdx.y * 4, b = blockIdx.z;
  float x[7];
  #pragma unroll
  for (int j = 0; j < 7; j++){
    int ls = l0 - 3 + j;
    x[j] = (ls >= 0) ? b2f(xdt[((size_t)(b * LTOT + ls)) * XDTC + ch]) : 0.f;
  }
  float w0 = cw[ch * 4 + 0], w1 = cw[ch * 4 + 1], w2 = cw[ch * 4 + 2], w3 = cw[ch * 4 + 3];
  float bias = cb[ch];
  #pragma unroll
  for (int i = 0; i < 4; i++){
    float acc = bias + x[i] * w0 + x[i + 1] * w1 + x[i + 2] * w2 + x[i + 3] * w3;
    acc = acc / (1.f + expf(-acc));
    xbc[((size_t)(b * LTOT + l0 + i)) * CONVD + ch] = f2b(acc);
  }
}

// ---------------- SSD part 2: states[p][n] = sum_l (x*dt*decay)[l][p] * B[l][n] ----------------
__global__ __launch_bounds__(256) void ssd_states_kernel(const unsigned short* __restrict__ xbc,
                                                         const float* __restrict__ dtb,
                                                         const float* __restrict__ acum,
                                                         unsigned short* __restrict__ states)
{
  int hh = blockIdx.x, c = blockIdx.y, b = blockIdx.z;
  __shared__ unsigned short BsT[128][136];  // [n][l]
  __shared__ unsigned short XT[64][136];    // [p][l]
  __shared__ float ac[128];
  int tid = threadIdx.x, lane = tid & 63, w = tid >> 6;
  size_t rowbase = (size_t)b * LTOT + c * CHUNK_;
  if (tid < 128) ac[tid] = acum[((size_t)(b * NH + hh)) * LTOT + c * CHUNK_ + tid];
  #pragma unroll
  for (int p = 0; p < 16; p++){
    int l = p * 8 + (tid >> 5);
    int n4 = (tid & 31) * 4;
    u16x4 v = *(const u16x4*)&xbc[(rowbase + l) * CONVD + DINNER + n4];
    BsT[n4 + 0][l] = v[0];
    BsT[n4 + 1][l] = v[1];
    BsT[n4 + 2][l] = v[2];
    BsT[n4 + 3][l] = v[3];
  }
  #pragma unroll
  for (int p = 0; p < 8; p++){
    int l = p * 16 + (tid >> 4);
    int p4 = (tid & 15) * 4;
    float dtl = dtb[(rowbase + l) * NH + hh];
    u16x4 v = *(const u16x4*)&xbc[(rowbase + l) * CONVD + hh * HD + p4];
    XT[p4 + 0][l] = f2b(b2f(v[0]) * dtl);
    XT[p4 + 1][l] = f2b(b2f(v[1]) * dtl);
    XT[p4 + 2][l] = f2b(b2f(v[2]) * dtl);
    XT[p4 + 3][l] = f2b(b2f(v[3]) * dtl);
  }
  __syncthreads();
  float aclast = ac[127];
  f32x4 accP[8] = {};
  #pragma unroll
  for (int kk = 0; kk < 4; kk++){
    int kbase = kk * 32 + (lane >> 4) * 8;
    union { u16x4 q[2]; unsigned short u[8]; bf16x8 v; } rw, ot;
    rw.q[0] = *(const u16x4*)&XT[w * 16 + (lane & 15)][kbase];
    rw.q[1] = *(const u16x4*)&XT[w * 16 + (lane & 15)][kbase + 4];
    #pragma unroll
    for (int e = 0; e < 8; e++){
      ot.u[e] = f2b(b2f(rw.u[e]) * expf(aclast - ac[kbase + e]));
    }
    #pragma unroll
    for (int fc = 0; fc < 8; fc++){
      bf16x8 bb = *(const bf16x8*)&BsT[fc * 16 + (lane & 15)][kbase];
      accP[fc] = mfma16(ot.v, bb, accP[fc]);
    }
  }
  size_t sbase = ((size_t)((b * NCH + c) * NH + hh)) * HD * DSTATE;
  int p0 = w * 16 + ((lane >> 4) << 2);
  #pragma unroll
  for (int fc = 0; fc < 8; fc++){
    int n = fc * 16 + (lane & 15);
    #pragma unroll
    for (int j = 0; j < 4; j++){
      states[sbase + (size_t)(p0 + j) * DSTATE + n] = f2b(accP[fc][j]);
    }
  }
}

// ---------------- SSD part 3: inter-chunk scan, in-place states -> prev; j split 8x ----------------
__global__ __launch_bounds__(256) void scan_kernel(unsigned short* __restrict__ states,
                                                   const float* __restrict__ acum)
{
  int bh = blockIdx.x;
  int b = bh >> 6, hh = bh & 63;
  int jg = blockIdx.y * 4;
  int t = threadIdx.x;
  float run[4] = {0.f, 0.f, 0.f, 0.f};
  for (int c = 0; c < NCH; c++){
    float alast = acum[(size_t)bh * LTOT + c * CHUNK_ + 127];
    float dec = expf(alast);
    size_t base = ((size_t)((b * NCH + c) * NH + hh)) * (HD * DSTATE);
    #pragma unroll
    for (int j = 0; j < 4; j++){
      size_t idx = base + (size_t)(jg + j) * 256 + t;
      float sc = b2f(states[idx]);
      states[idx] = f2b(run[j]);
      run[j] = run[j] * dec + sc;
    }
  }
}

// ---------------- FUSED SSD-Y: y = Y_diag + Y_off + D*x, one bf16 write ----------------
// Per (hh, chunk-half, b). accY accumulates BOTH matmuls (same output tile):
//   pass A (before Cs overwrite): accY += (C·exp(ac[l]))·prev^T   [k-dim = n (128)]
//   pass B (after S'/XT built):   accY += S'·XT                   [k-dim = s (128)]
// Dynamic LDS: Cs 64x136 | Bs 128x136 | Ps 64x136 | ac[128]  = 70,144 B -> 2 blocks/CU.
__global__ __launch_bounds__(256, 2) void ssd_y_kernel(const unsigned short* __restrict__ xbc,
                                                       const unsigned short* __restrict__ states,
                                                       const float* __restrict__ dtb,
                                                       const float* __restrict__ acum,
                                                       const float* __restrict__ Dp,
                                                       unsigned short* __restrict__ y)
{
  extern __shared__ unsigned short lds[];
  unsigned short* Cs = lds;                 // [64][136]
  unsigned short* Bs = lds + 8704;          // [128][136]
  unsigned short* Ps = lds + 26112;         // [64][136]
  float* ac = (float*)(lds + 34816);        // [128]
  #define CS(r, cix) Cs[(r) * 136 + (cix)]
  #define BS(r, cix) Bs[(r) * 136 + (cix)]
  #define PS(r, cix) Ps[(r) * 136 + (cix)]
  int hh = blockIdx.x;
  int c = blockIdx.y >> 1;
  int half = blockIdx.y & 1;
  int b = blockIdx.z;
  int tid = threadIdx.x, lane = tid & 63, w = tid >> 6;
  int l0 = half * 64;
  size_t rowbase = (size_t)b * LTOT + c * CHUNK_;
  if (tid < 128) ac[tid] = acum[((size_t)(b * NH + hh)) * LTOT + c * CHUNK_ + tid];
  #pragma unroll
  for (int p = 0; p < 8; p++){
    int lr = p * 8 + (tid >> 5);
    int n4 = (tid & 31) * 4;
    *(u16x4*)&CS(lr, n4) =
      *(const u16x4*)&xbc[(rowbase + l0 + lr) * CONVD + DINNER + DSTATE + n4];
  }
  #pragma unroll
  for (int p = 0; p < 16; p++){
    int s = p * 8 + (tid >> 5);
    int n4 = (tid & 31) * 4;
    *(u16x4*)&BS(s, n4) = *(const u16x4*)&xbc[(rowbase + s) * CONVD + DINNER + n4];
  }
  size_t sbase = ((size_t)((b * NCH + c) * NH + hh)) * (HD * DSTATE);
  #pragma unroll
  for (int p = 0; p < 8; p++){
    int pp = p * 8 + (tid >> 5);
    int n4 = (tid & 31) * 4;
    *(u16x4*)&PS(pp, n4) = *(const u16x4*)&states[sbase + (size_t)pp * DSTATE + n4];
  }
  __syncthreads();
  // pass 1: accS = C·B^T  (rows l, cols s)
  f32x4 accS[8] = {};
  #pragma unroll
  for (int kk = 0; kk < 4; kk++){
    bf16x8 a = *(const bf16x8*)&CS(w * 16 + (lane & 15), kk * 32 + (lane >> 4) * 8);
    #pragma unroll
    for (int fc = 0; fc < 8; fc++){
      bf16x8 bb = *(const bf16x8*)&BS(fc * 16 + (lane & 15), kk * 32 + (lane >> 4) * 8);
      accS[fc] = mfma16(a, bb, accS[fc]);
    }
  }
  // pass 2: accY = (C * exp(ac[l])) · prev^T   (rows l, cols p; k = n)
  f32x4 accY[4] = {};
  {
    int arow = w * 16 + (lane & 15);
    float el = expf(ac[l0 + arow]);
    #pragma unroll
    for (int kk = 0; kk < 4; kk++){
      int kbase = kk * 32 + (lane >> 4) * 8;
      union { u16x4 q[2]; unsigned short u[8]; bf16x8 v; } cf;
      cf.q[0] = *(const u16x4*)&CS(arow, kbase);
      cf.q[1] = *(const u16x4*)&CS(arow, kbase + 4);
      #pragma unroll
      for (int e = 0; e < 8; e++) cf.u[e] = f2b(b2f(cf.u[e]) * el);
      #pragma unroll
      for (int fc = 0; fc < 4; fc++){
        bf16x8 bb = *(const bf16x8*)&PS(fc * 16 + (lane & 15), kbase);
        accY[fc] = mfma16(cf.v, bb, accY[fc]);
      }
    }
  }
  __syncthreads();
  // S' into Cs (transposed: row l-local, col s)
  {
    int lr = w * 16 + ((lane >> 4) << 2);
    #pragma unroll
    for (int fc = 0; fc < 8; fc++){
      int s = fc * 16 + (lane & 15);
      #pragma unroll
      for (int j = 0; j < 4; j++){
        int l = l0 + lr + j;
        float v = (s <= l) ? accS[fc][j] * expf(ac[l] - ac[s]) : 0.f;
        CS(lr + j, s) = f2b(v);
      }
    }
  }
  // XT = (x*dt)^T into Bs rows 0..63
  #pragma unroll
  for (int p = 0; p < 8; p++){
    int lr = p * 16 + (tid >> 4);
    int p4 = (tid & 15) * 4;
    float dtl = dtb[(rowbase + lr) * NH + hh];
    u16x4 v = *(const u16x4*)&xbc[(rowbase + lr) * CONVD + hh * HD + p4];
    BS(p4 + 0, lr) = f2b(b2f(v[0]) * dtl);
    BS(p4 + 1, lr) = f2b(b2f(v[1]) * dtl);
    BS(p4 + 2, lr) = f2b(b2f(v[2]) * dtl);
    BS(p4 + 3, lr) = f2b(b2f(v[3]) * dtl);
  }
  __syncthreads();
  // pass 3: accY += S'·XT
  #pragma unroll
  for (int kk = 0; kk < 4; kk++){
    bf16x8 a = *(const bf16x8*)&CS(w * 16 + (lane & 15), kk * 32 + (lane >> 4) * 8);
    #pragma unroll
    for (int fc = 0; fc < 4; fc++){
      bf16x8 bb = *(const bf16x8*)&BS(fc * 16 + (lane & 15), kk * 32 + (lane >> 4) * 8);
      accY[fc] = mfma16(a, bb, accY[fc]);
    }
  }
  // epilogue: y = accY + D*x, bf16 once
  float dpar = Dp[hh];
  {
    int lr = w * 16 + ((lane >> 4) << 2);
    #pragma unroll
    for (int fc = 0; fc < 4; fc++){
      int p = fc * 16 + (lane & 15);
      #pragma unroll
      for (int j = 0; j < 4; j++){
        int l = l0 + lr + j;
        float xsv = b2f(xbc[(rowbase + l) * CONVD + hh * HD + p]);
        y[(rowbase + l) * DINNER + hh * HD + p] = f2b(accY[fc][j] + dpar * xsv);
      }
    }
  }
  #undef CS
  #undef BS
  #undef PS
}

extern "C" void kernel_launch(void* const* d_in, const int* in_sizes, int n_in,
                              void* d_out, int out_size, void* d_ws, size_t ws_size,
                              hipStream_t stream)
{
  (void)in_sizes; (void)n_in; (void)out_size; (void)ws_size;
  const float* hidden    = (const float*)d_in[0];
  const float* norm1_w   = (const float*)d_in[1];
  const float* in_proj_w = (const float*)d_in[2];
  const float* conv_w    = (const float*)d_in[3];
  const float* conv_b    = (const float*)d_in[4];
  const float* dt_bias   = (const float*)d_in[5];
  const float* A_log     = (const float*)d_in[6];
  const float* D_param   = (const float*)d_in[7];
  const float* mixer_w   = (const float*)d_in[8];
  const float* out_proj_w= (const float*)d_in[9];
  const float* norm2_w   = (const float*)d_in[10];
  const float* gate_w    = (const float*)d_in[11];
  const float* up_w      = (const float*)d_in[12];
  const float* down_w    = (const float*)d_in[13];

  char* ws = (char*)d_ws;
  unsigned short* zbuf    = (unsigned short*)(ws);                  // bf16 4096x4096 [k2..k10]
  unsigned short* WT_cat  = (unsigned short*)(ws);                  // bf16 11264x2048 interleaved [k12.5..k13]
  unsigned short* WT_down = (unsigned short*)(ws);                  // bf16 2048x5632 [k14..k15]
  unsigned short* xdt     = (unsigned short*)(ws + 33554432ull);    // bf16 4096x4416 [k2..k5]
  unsigned short* states  = (unsigned short*)(ws + 33554432ull);    // bf16 16.7M el  [k7..k9]
  unsigned short* ygn     = (unsigned short*)(ws + 33554432ull);    // bf16 4096x4096 [k10..k11]
  unsigned short* xbc     = (unsigned short*)(ws + 69730304ull);    // bf16 4096x4352 [k5..k9]
  unsigned short* WT_out  = (unsigned short*)(ws + 69730304ull);    // bf16 2048x4096 [k10.5..k11]
  float* dtraw            = (float*)(ws + 105381888ull);            // f32 4096x64 [k2..k3]
  float* dtb              = (float*)(ws + 106430464ull);            // f32 4096x64 [k3..k9]
  float* acum             = (float*)(ws + 107479040ull);            // f32 128x2048 [k4..k9]
  unsigned short* ybb     = (unsigned short*)(ws + 108527616ull);   // bf16 4096x4096 [k6..k10]
  unsigned short* hbuf    = (unsigned short*)(ws + 108527616ull);   // bf16 4096x2048 [k1..k2]
  unsigned short* gbuf    = (unsigned short*)(ws + 108527616ull);   // bf16 4096x5632 [k13..k15]
  unsigned short* WT_in   = (unsigned short*)(ws + 125304832ull);   // bf16 8704x2048 [k0..k2]
  unsigned short* h2      = (unsigned short*)(ws + 154664960ull);   // bf16 4096x2048 [k12..k13]
  float* h1               = (float*)d_out;
  float* outp             = (float*)d_out;

  const int dynLDS3 = 73728;   // 3 x 24KB -> 2 blocks/CU
  const int dynLDS4 = 49152;   // 3 x 16KB -> 3 blocks/CU
  const int dynLDSY = 70144;   // Cs+Bs+Ps+ac -> 2 blocks/CU
  hipFuncSetAttribute((const void*)gemm3_kernel,
                      hipFuncAttributeMaxDynamicSharedMemorySize, dynLDS3);
  hipFuncSetAttribute((const void*)gemm4_kernel,
                      hipFuncAttributeMaxDynamicSharedMemorySize, dynLDS4);
  hipFuncSetAttribute((const void*)ssd_y_kernel,
                      hipFuncAttributeMaxDynamicSharedMemorySize, dynLDSY);

  // 0. convert in_proj weight -> bf16 [8704][2048]
  wconv_kernel<<<dim3(136, 32), 256, 0, stream>>>(in_proj_w, WT_in, DMODEL, INP, 1, 0);
  // 1. h = rmsnorm(hidden) -> bf16
  rms_kernel<<<NTOK, 256, 0, stream>>>(hidden, norm1_w, hbuf, DMODEL);
  // 2. zxbcdt = h @ in_proj
  gemm3_kernel<<<dim3(34, 32), 512, dynLDS3, stream>>>(hbuf, WT_in, nullptr, nullptr,
                                                       zbuf, xdt, DINNER, 0, dtraw,
                                                       NTOK, INP, DMODEL);
  // 3+4. fused softplus + cumsum
  acum_kernel<<<BATCH * NH * NCH, 64, 0, stream>>>(dtraw, dt_bias, A_log, dtb, acum);
  // 5. conv + silu
  conv_kernel<<<dim3(CONVD / 256, LTOT / 4, BATCH), 256, 0, stream>>>(xdt, conv_w, conv_b, xbc);
  // 6. SSD per-chunk states
  ssd_states_kernel<<<dim3(NH, NCH, BATCH), 256, 0, stream>>>(xbc, dtb, acum, states);
  // 7. inter-chunk scan (in-place -> prev)
  scan_kernel<<<dim3(BATCH * NH, 8), 256, 0, stream>>>(states, acum);
  // 8. FUSED Y: Y_diag + Y_off + D*x -> ybb (bf16, one write)
  ssd_y_kernel<<<dim3(NH, NCH * 2, BATCH), 256, dynLDSY, stream>>>(xbc, states, dtb, acum,
                                                                   D_param, ybb);
  // 9. gated rmsnorm: ygn = rmsnorm(y * silu(z))
  rms_gated_kernel<<<NTOK, 256, 0, stream>>>(ybb, zbuf, mixer_w, ygn);
  // 9.5 convert out_proj weight
  wconv_kernel<<<dim3(32, 64), 256, 0, stream>>>(out_proj_w, WT_out, DINNER, DMODEL, 1, 0);
  // 10. h1 = hidden + ygn @ out_proj (into d_out)
  gemm4_kernel<<<dim3(16, 32), 256, dynLDS4, stream>>>(ygn, WT_out, hidden, h1,
                                                       NTOK, DMODEL, DINNER);
  // 11. h2 = rmsnorm(h1) -> bf16
  rms_kernel<<<NTOK, 256, 0, stream>>>(h1, norm2_w, h2, DMODEL);
  // 11.5 convert gate+up weights, column-interleaved
  wconv_kernel<<<dim3(88, 32), 256, 0, stream>>>(gate_w, WT_cat, DMODEL, INTER_, 2, 0);
  wconv_kernel<<<dim3(88, 32), 256, 0, stream>>>(up_w, WT_cat, DMODEL, INTER_, 2, 1);
  // 12. fused gate+up GEMM with GLU epilogue
  gemm3_kernel<<<dim3(44, 32), 512, dynLDS3, stream>>>(h2, WT_cat, nullptr, nullptr,
                                                       gbuf, nullptr, 0, 1, nullptr,
                                                       NTOK, 2 * INTER_, DMODEL);
  // 13. convert down weight
  wconv_kernel<<<dim3(32, 88), 256, 0, stream>>>(down_w, WT_down, INTER_, DMODEL, 1, 0);
  // 14. out = h1 + (g*u) @ down_w (in place on d_out)
  gemm4_kernel<<<dim3(16, 32), 256, dynLDS4, stream>>>(gbuf, WT_down, h1, outp,
                                                       NTOK, DMODEL, INTER_);
}